// Round 3
// baseline (58255.988 us; speedup 1.0000x reference)
//
#include <hip/hip_runtime.h>

// Problem sizes (fixed by reference)
#define BB 32
#define TT 512
#define DD 512
#define HH 512
#define LL 4
#define HB (HH * BB)           // 16384
#define NWG 192
#define TPB 512

// ws: data floats then flag/counter slots (memset to 0 by host each call)
#define STATE_FLOATS (LL * 2 * HB)              // 131072
#define GATE_FLOATS  (3 * LL * HB)              // 196608
#define DATA_FLOATS  (STATE_FLOATS + GATE_FLOATS)
#define FLAG_STRIDE  64                          // 256 B per counter slot
#define NFLAG        209                         // keep prior ws footprint
#define FLAGS_BYTES  ((unsigned long long)NFLAG * FLAG_STRIDE * 4ull)
#define WS_NEED_BYTES ((unsigned long long)DATA_FLOATS * 4ull + FLAGS_BYTES)
#define LDS_BYTES 131072       // 128 KB resident weights

// ---- self-timed dataflow, split per-gate counters ----
// CNT(i,g): g=0 z (16 posts/step), 1 r (16), 2 hU (8), 3 B (8).
// Deps per step t (combined per-phase poll, lane-parallel):
//   A(i,t):  CB(i-1) >= 8(t+1) [i>0; inp ready]  AND  CB(i) >= 8t
//            (prev state ready + gate-buffer overwrite ack)
//   B(i,t):  CZ(i),CR(i) >= 16(t+1), CH(i) >= 8(t+1)  (gates of step t;
//            own prow trivially ready: same WG wrote it at t-1)
//            + state(t-2)-slot overwrite ack: readers are A(i+1,t-2) ->
//            CZ/CR(i+1) >= 16(t-1), CH(i+1) >= 8(t-1)   [i<3]
// Publication: relaxed agent-scope atomic stores (write through to IC),
// s_waitcnt(0) all threads + barrier, thread0 atomicAdd (R0/R1-proven).
// Consumption: lanes 0..5 of wave 0 poll counters in parallel (divergent
// spin), ONE acquire fence (L1/L2 inv), barrier, then PLAIN vectorized
// loads (compiler-pipelined) read IC-fresh data. NO atomic data loads
// (R2 lesson: hipcc serializes them -> 2x regression).
// All cross-WG float buffers use GRANULE layout [col/4][b][4]: a wave's
// float4 load (lanes span b) is 512B contiguous = 1-2 cache lines, vs 32
// scattered lines in the old [b][col] layout.
#define CNT(f, i, g) ((f) + (((i) * 4 + (g)) * FLAG_STRIDE))
#define SPIN_CAP (1 << 20)     // ~0.1-0.3 s, then free-run via s_dead (no hang)

#define GIDX(g, b)   (((g) * 32 + (b)) * 4)                    // granule g, row b
#define CIDX(col, b) ((((col) >> 2) * 32 + (b)) * 4 + ((col) & 3))

__device__ __forceinline__ void poll1(volatile int* sdead, int* c, int tgt) {
    int spins = 0;
    while (*sdead == 0 &&
           __hip_atomic_load(c, __ATOMIC_RELAXED, __HIP_MEMORY_SCOPE_AGENT) < tgt) {
        __builtin_amdgcn_s_sleep(1);
        if (++spins > SPIN_CAP) { *sdead = 1; break; }
    }
}

__device__ __forceinline__ void wg_post(int* cnt) {
    asm volatile("" ::: "memory");
    __builtin_amdgcn_s_waitcnt(0);   // own stores ack'd at coherence point
    __syncthreads();                 // all threads drained
    if (threadIdx.x == 0)
        atomicAdd(cnt, 1);           // device-scope, IC-level
}

__device__ __forceinline__ void pub_store(float* p, float v) {
    __hip_atomic_store(p, v, __ATOMIC_RELAXED, __HIP_MEMORY_SCOPE_AGENT);
}

// WG roles (logical wg 0..191), TPB=512: b=tid&31, cg=tid>>5 (0..15).
//   wg   0..127: A z/r. grp=wg>>4: i=grp>>1, g=grp&1; 32 cols (2/thread)
//                LDS packed: lds[(k*16+cg)*4] = {U[k][c],U[k][c+16],
//                                                W[k][c],W[k][c+16]}
//   wg 128..159: A hU.  i=(wg-128)>>3; 64 cols (4/thread)
//                LDS: lds[(k*16+q)*4] = {M[k][q],M[k][q+16],M[k][q+32],M[k][q+48]}
//   wg 160..191: B.     i=(wg-160)>>3; 64 cols (4/thread); LDS as hU with W2.
// Weight LDS reads: per wave, 2 distinct cg values -> 32-lane broadcast each,
// conflict-free.

__global__ __launch_bounds__(TPB) void gru_wave(
    const float* __restrict__ x,    // [B,T,D]
    const float* __restrict__ Wp,   // [L,3,H,H]
    const float* __restrict__ Up,   // [L,3,D,H]
    float* __restrict__ out,        // [B,T,H]
    float* __restrict__ ws)
{
    extern __shared__ float lds[];  // 32768 floats
    __shared__ int s_dead;

    const int bid = blockIdx.x;
    const int wg  = (bid & 7) * 24 + (bid >> 3);   // XCD-contiguous logical id
    const int tid = threadIdx.x;
    const int b   = tid & 31;
    const int cg  = tid >> 5;          // 0..15

    float* state = ws;                         // [L][2] slices, granule layout
    float* zbuf  = state + LL * 2 * HB;        // [L] slices, granule layout
    float* rbuf  = zbuf + LL * HB;
    float* hUbuf = rbuf + LL * HB;
    int*   flags = (int*)(ws + DATA_FLOATS);

    const bool isZR = wg < 128;
    const bool isHU = (wg >= 128) && (wg < 160);

    int iA = 0, gA = 0, col0 = 0, iB = 0, col0B = 0;
    if (isZR) { int grp = wg >> 4; iA = grp >> 1; gA = grp & 1; col0 = (wg & 15) * 32; }
    else if (isHU) { int w2 = wg - 128; iA = w2 >> 3; col0 = (w2 & 7) * 64; }
    else { int w3 = wg - 160; iB = w3 >> 3; col0B = (w3 & 7) * 64; }

    // ---- one-time weight staging into resident LDS (plain loads) ----
    if (isZR) {
        const float* Um = Up + (size_t)(iA * 3 + gA) * DD * HH + col0;
        const float* Wm = Wp + (size_t)(iA * 3 + gA) * HH * HH + col0;
        for (int u = tid; u < 8192; u += TPB) {      // u = k*16 + cc
            int k = u >> 4, cc = u & 15;
            const float* ur = Um + (size_t)k * HH + cc;
            const float* wr = Wm + (size_t)k * HH + cc;
            *(float4*)&lds[u * 4] = make_float4(ur[0], ur[16], wr[0], wr[16]);
        }
    } else {
        const float* Mm = isHU ? (Up + (size_t)(iA * 3 + 2) * DD * HH + col0)
                               : (Wp + (size_t)(iB * 3 + 2) * HH * HH + col0B);
        for (int u = tid; u < 8192; u += TPB) {      // u = k*16 + q
            int k = u >> 4, q = u & 15;
            const float* mr = Mm + (size_t)k * HH + q;
            *(float4*)&lds[u * 4] = make_float4(mr[0], mr[16], mr[32], mr[48]);
        }
    }
    if (tid == 0) s_dead = 0;
    __syncthreads();

    if (isZR) {
        float* dst = (gA == 0 ? zbuf : rbuf) + (size_t)iA * HB;
        int* cb_up = (iA > 0) ? CNT(flags, iA - 1, 3) : nullptr;
        int* cb_my = CNT(flags, iA, 3);
        int* c_my  = CNT(flags, iA, gA);
        const int colA = col0 + cg;          // outputs colA, colA+16
        for (int t = 0; t < TT; ++t) {
            if (tid < 64) {
                int* cp = nullptr; int tgt = 0;
                if (tid == 0) { cp = cb_my; tgt = 8 * t; }
                else if (tid == 1 && cb_up) { cp = cb_up; tgt = 8 * (t + 1); }
                if (cp) poll1(&s_dead, cp, tgt);
                __builtin_amdgcn_fence(__ATOMIC_ACQUIRE, "agent");
            }
            __syncthreads();
            const float* prow = state + (size_t)(iA * 2 + ((t + 1) & 1)) * HB;
            float a0 = 0.f, a1 = 0.f;
            if (iA == 0) {
                const float* urow = x + ((size_t)b * TT + t) * DD;
                #pragma unroll 8
                for (int g = 0; g < 128; ++g) {
                    float4 xi = *(const float4*)&urow[g * 4];
                    float4 pi = *(const float4*)&prow[GIDX(g, b)];
                    #pragma unroll
                    for (int j = 0; j < 4; ++j) {
                        float4 q = *(const float4*)&lds[((g * 4 + j) * 16 + cg) * 4];
                        float xv = (&xi.x)[j], pv = (&pi.x)[j];
                        a0 = fmaf(xv, q.x, a0); a1 = fmaf(xv, q.y, a1);
                        a0 = fmaf(pv, q.z, a0); a1 = fmaf(pv, q.w, a1);
                    }
                }
            } else {
                const float* urow = state + (size_t)((iA - 1) * 2 + (t & 1)) * HB;
                #pragma unroll 8
                for (int g = 0; g < 128; ++g) {
                    float4 xi = *(const float4*)&urow[GIDX(g, b)];
                    float4 pi = *(const float4*)&prow[GIDX(g, b)];
                    #pragma unroll
                    for (int j = 0; j < 4; ++j) {
                        float4 q = *(const float4*)&lds[((g * 4 + j) * 16 + cg) * 4];
                        float xv = (&xi.x)[j], pv = (&pi.x)[j];
                        a0 = fmaf(xv, q.x, a0); a1 = fmaf(xv, q.y, a1);
                        a0 = fmaf(pv, q.z, a0); a1 = fmaf(pv, q.w, a1);
                    }
                }
            }
            pub_store(&dst[CIDX(colA, b)],      1.0f / (1.0f + __expf(-a0)));
            pub_store(&dst[CIDX(colA + 16, b)], 1.0f / (1.0f + __expf(-a1)));
            wg_post(c_my);
        }
    } else if (isHU) {
        float* hu = hUbuf + (size_t)iA * HB;
        int* cb_up = (iA > 0) ? CNT(flags, iA - 1, 3) : nullptr;
        int* cb_my = CNT(flags, iA, 3);
        int* c_my  = CNT(flags, iA, 2);
        const int colA = col0 + cg;          // outputs colA + {0,16,32,48}
        for (int t = 0; t < TT; ++t) {
            if (tid < 64) {
                int* cp = nullptr; int tgt = 0;
                if (tid == 0) { cp = cb_my; tgt = 8 * t; }
                else if (tid == 1 && cb_up) { cp = cb_up; tgt = 8 * (t + 1); }
                if (cp) poll1(&s_dead, cp, tgt);
                if (cb_up)   // layer 0 reads only x (read-only): no inv needed
                    __builtin_amdgcn_fence(__ATOMIC_ACQUIRE, "agent");
            }
            __syncthreads();
            float a0 = 0.f, a1 = 0.f, a2 = 0.f, a3 = 0.f;
            if (iA == 0) {
                const float* urow = x + ((size_t)b * TT + t) * DD;
                #pragma unroll 8
                for (int g = 0; g < 128; ++g) {
                    float4 xi = *(const float4*)&urow[g * 4];
                    #pragma unroll
                    for (int j = 0; j < 4; ++j) {
                        float4 q = *(const float4*)&lds[((g * 4 + j) * 16 + cg) * 4];
                        float xv = (&xi.x)[j];
                        a0 = fmaf(xv, q.x, a0); a1 = fmaf(xv, q.y, a1);
                        a2 = fmaf(xv, q.z, a2); a3 = fmaf(xv, q.w, a3);
                    }
                }
            } else {
                const float* urow = state + (size_t)((iA - 1) * 2 + (t & 1)) * HB;
                #pragma unroll 8
                for (int g = 0; g < 128; ++g) {
                    float4 xi = *(const float4*)&urow[GIDX(g, b)];
                    #pragma unroll
                    for (int j = 0; j < 4; ++j) {
                        float4 q = *(const float4*)&lds[((g * 4 + j) * 16 + cg) * 4];
                        float xv = (&xi.x)[j];
                        a0 = fmaf(xv, q.x, a0); a1 = fmaf(xv, q.y, a1);
                        a2 = fmaf(xv, q.z, a2); a3 = fmaf(xv, q.w, a3);
                    }
                }
            }
            pub_store(&hu[CIDX(colA,      b)], a0);
            pub_store(&hu[CIDX(colA + 16, b)], a1);
            pub_store(&hu[CIDX(colA + 32, b)], a2);
            pub_store(&hu[CIDX(colA + 48, b)], a3);
            wg_post(c_my);
        }
    } else {
        const float* rrow = rbuf + (size_t)iB * HB;
        const float* hu   = hUbuf + (size_t)iB * HB;
        const float* zz   = zbuf + (size_t)iB * HB;
        int* c_my = CNT(flags, iB, 3);
        const int colA = col0B + cg;         // outputs colA + {0,16,32,48}
        for (int t = 0; t < TT; ++t) {
            if (tid < 64) {
                int* cp = nullptr; int tgt = 0;
                if (tid == 0)      { cp = CNT(flags, iB, 1); tgt = 16 * (t + 1); }
                else if (tid == 1) { cp = CNT(flags, iB, 0); tgt = 16 * (t + 1); }
                else if (tid == 2) { cp = CNT(flags, iB, 2); tgt =  8 * (t + 1); }
                else if (iB < LL - 1) {
                    if (tid == 3)      { cp = CNT(flags, iB + 1, 0); tgt = 16 * (t - 1); }
                    else if (tid == 4) { cp = CNT(flags, iB + 1, 1); tgt = 16 * (t - 1); }
                    else if (tid == 5) { cp = CNT(flags, iB + 1, 2); tgt =  8 * (t - 1); }
                }
                if (cp) poll1(&s_dead, cp, tgt);
                __builtin_amdgcn_fence(__ATOMIC_ACQUIRE, "agent");
            }
            __syncthreads();
            const float* prow = state + (size_t)(iB * 2 + ((t + 1) & 1)) * HB;
            float a0 = 0.f, a1 = 0.f, a2 = 0.f, a3 = 0.f;
            #pragma unroll 8
            for (int g = 0; g < 128; ++g) {
                float4 ri = *(const float4*)&rrow[GIDX(g, b)];
                float4 pi = *(const float4*)&prow[GIDX(g, b)];
                #pragma unroll
                for (int j = 0; j < 4; ++j) {
                    float rp = (&ri.x)[j] * (&pi.x)[j];
                    float4 q = *(const float4*)&lds[((g * 4 + j) * 16 + cg) * 4];
                    a0 = fmaf(rp, q.x, a0); a1 = fmaf(rp, q.y, a1);
                    a2 = fmaf(rp, q.z, a2); a3 = fmaf(rp, q.w, a3);
                }
            }
            float* stNew = state + (size_t)(iB * 2 + (t & 1)) * HB;
            float acc[4] = {a0, a1, a2, a3};
            #pragma unroll
            for (int j = 0; j < 4; ++j) {
                const int col = colA + j * 16;
                float a2v = acc[j] + hu[CIDX(col, b)];
                float h   = tanhf(a2v);
                float zg  = zz[CIDX(col, b)];
                float pv  = prow[CIDX(col, b)];          // L1-hot (read in GEMV)
                float s   = zg * (pv - h) + h;           // (1-z)*h + z*prev
                pub_store(&stNew[CIDX(col, b)], s);
                if (iB == LL - 1)
                    out[((size_t)b * TT + t) * HH + col] = s;
            }
            wg_post(c_my);
        }
    }
}

extern "C" void kernel_launch(void* const* d_in, const int* in_sizes, int n_in,
                              void* d_out, int out_size, void* d_ws, size_t ws_size,
                              hipStream_t stream) {
    const float* x  = (const float*)d_in[0];  // [32,512,512]
    const float* Wp = (const float*)d_in[1];  // [4,3,512,512]
    const float* Up = (const float*)d_in[2];  // [4,3,512,512]
    float* out = (float*)d_out;
    float* ws  = (float*)d_ws;

    // Sentinel 1: workspace too small -> absmax ~8.5e37
    if (ws_size < WS_NEED_BYTES) {
        hipMemsetAsync(d_out, 0x7e, (size_t)out_size * sizeof(float), stream);
        return;
    }

    // Host-side zero of state (t=0 prev) and counters each call.
    // State is only written by IC-level atomic stores in-kernel, so host
    // memset keeps it free of dirty L2 aliases.
    hipMemsetAsync(ws, 0, (size_t)STATE_FLOATS * sizeof(float), stream);
    hipMemsetAsync(ws + DATA_FLOATS, 0, FLAGS_BYTES, stream);

    hipLaunchKernelGGL(gru_wave, dim3(NWG), dim3(TPB), LDS_BYTES, stream,
                       x, Wp, Up, out, ws);
    // Sentinel 2: launch rejected -> absmax ~3.4e38
    hipError_t err = hipGetLastError();
    if (err != hipSuccess)
        hipMemsetAsync(d_out, 0x7f, (size_t)out_size * sizeof(float), stream);
}

// Round 4
// 47732.037 us; speedup vs baseline: 1.2205x; 1.2205x over previous
//
#include <hip/hip_runtime.h>

// Problem sizes (fixed by reference)
#define BB 32
#define TT 512
#define DD 512
#define HH 512
#define LL 4
#define HB (HH * BB)           // 16384
#define NWG 192
#define TPB 256

// ws: data floats then flag/counter slots (memset to 0 by host each call)
#define STATE_FLOATS (LL * 2 * HB)              // 131072
#define GATE_FLOATS  (3 * LL * HB)              // 196608
#define DATA_FLOATS  (STATE_FLOATS + GATE_FLOATS)
#define FLAG_STRIDE  64                          // 256 B per counter slot
#define NFLAG        209                         // keep prior ws footprint
#define FLAGS_BYTES  ((unsigned long long)NFLAG * FLAG_STRIDE * 4ull)
#define WS_NEED_BYTES ((unsigned long long)DATA_FLOATS * 4ull + FLAGS_BYTES)
#define LDS_BYTES 131072       // 128 KB resident weights

// ---- self-timed dataflow, split per-gate counters (R1 schedule) ----
// CNT(i,g): g=0 z (16 posts/step), 1 r (16), 2 hU (8), 3 B (8).
// Deps per step t:
//   A(i,t):  U-side needs CB(i-1) >= 8(t+1) [i>0; fence]   (overlapped: U-GEMV
//            runs before the recurrent wait)
//            W-side / stores need CB(i) >= 8t (prev ready + gate ack; fence
//            for ZR which reads prow; NO fence for hU, nothing read after)
//   B(i,t):  GEMV needs CR(i) >= 16(t+1) (fence). Sufficiency: r-WGs waited
//            CB(i)>=8t before their W-GEMV, so CR>=16(t+1) => prow complete
//            at IC; our fence makes it visible.
//            Epilogue needs CZ(i) >= 16(t+1), CH(i) >= 8(t+1) (z/hU data) and
//            state(t-2)-slot overwrite ack: readers are A(i+1,t-2) ->
//            CZ/CR(i+1) >= 16(t-1), CH(i+1) >= 8(t-1) [i<3]. One fence after.
// Publication: relaxed agent-scope atomic stores (write through to IC),
// s_waitcnt(0) all threads + barrier, thread0 atomicAdd (R0/R1-proven).
// Consumption: tid0 (or tids 0..4 in parallel) poll relaxed, ONE acquire
// fence (L1/L2 inv), barrier, then PLAIN vectorized loads (R2 lesson: atomic
// data loads serialize -> never again).
// Cross-WG float buffers use GRANULE layout [col/4][b][4]: a wave float4
// load (lanes span b) is 512B contiguous (8 lines) instead of 32 scattered
// lines (R3-proven: WRITE_SIZE halved).
// MLP: __launch_bounds__(TPB,1) (only 1 WG/CU fits at 128KB LDS) frees the
// VGPR budget so unroll-8 keeps many loads in flight (R1 had VGPR=56 -> ~8
// outstanding; that latency exposure is the modeled 40us/step).
#define CNT(f, i, g) ((f) + (((i) * 4 + (g)) * FLAG_STRIDE))
#define SPIN_CAP (1 << 21)     // ~0.3 s, then free-run via s_dead (no hang)

#define GIDX(g, b)   (((g) * 32 + (b)) * 4)                    // granule g, row b
#define CIDX(col, b) ((((col) >> 2) * 32 + (b)) * 4 + ((col) & 3))

__device__ __forceinline__ void poll1(volatile int* sdead, int* c, int tgt) {
    int spins = 0;
    while (*sdead == 0 &&
           __hip_atomic_load(c, __ATOMIC_RELAXED, __HIP_MEMORY_SCOPE_AGENT) < tgt) {
        __builtin_amdgcn_s_sleep(1);
        if (++spins > SPIN_CAP) { *sdead = 1; break; }
    }
}

__device__ __forceinline__ void wg_post(int* cnt) {
    asm volatile("" ::: "memory");
    __builtin_amdgcn_s_waitcnt(0);   // own stores ack'd at coherence point
    __syncthreads();                 // all threads drained
    if (threadIdx.x == 0)
        atomicAdd(cnt, 1);           // device-scope, IC-level
}

__device__ __forceinline__ void pub_store(float* p, float v) {
    __hip_atomic_store(p, v, __ATOMIC_RELAXED, __HIP_MEMORY_SCOPE_AGENT);
}

// WG roles (logical wg 0..191), TPB=256: b=tid&31, c=tid>>5 (0..7).
//   wg   0..127: A z/r. grp=wg>>4: i=grp>>1, g=grp&1; 32 cols (4/thread)
//                LDS: lds[(k*8+c)*4]        = {U[k][c],U[k][c+8],U[k][c+16],U[k][c+24]}
//                     lds[16384+(k*8+c)*4]  = same for W
//   wg 128..159: A hU.  i=(wg-128)>>3; 64 cols (8/thread)
//                LDS: lds[(k*16+q)*4] = {M[k][q],M[k][q+16],M[k][q+32],M[k][q+48]}
//   wg 160..191: B.     i=(wg-160)>>3; 64 cols (8/thread); LDS as hU with W2.
// Weight LDS reads: per wave 2 distinct c values -> 32-lane broadcast each,
// conflict-free (2-way aliasing is free on CDNA4).

__global__ __launch_bounds__(TPB, 1) void gru_wave(
    const float* __restrict__ x,    // [B,T,D]
    const float* __restrict__ Wp,   // [L,3,H,H]
    const float* __restrict__ Up,   // [L,3,D,H]
    float* __restrict__ out,        // [B,T,H]
    float* __restrict__ ws)
{
    extern __shared__ float lds[];  // 32768 floats
    __shared__ int s_dead;

    const int bid = blockIdx.x;
    const int wg  = (bid & 7) * 24 + (bid >> 3);   // XCD-contiguous logical id
    const int tid = threadIdx.x;
    const int b   = tid & 31;
    const int c   = tid >> 5;          // 0..7

    float* state = ws;                         // [L][2] slices, granule layout
    float* zbuf  = state + LL * 2 * HB;        // [L] slices, granule layout
    float* rbuf  = zbuf + LL * HB;
    float* hUbuf = rbuf + LL * HB;
    int*   flags = (int*)(ws + DATA_FLOATS);

    const bool isZR = wg < 128;
    const bool isHU = (wg >= 128) && (wg < 160);

    int iA = 0, gA = 0, col0 = 0, iB = 0, col0B = 0;
    if (isZR) { int grp = wg >> 4; iA = grp >> 1; gA = grp & 1; col0 = (wg & 15) * 32; }
    else if (isHU) { int w2 = wg - 128; iA = w2 >> 3; col0 = (w2 & 7) * 64; }
    else { int w3 = wg - 160; iB = w3 >> 3; col0B = (w3 & 7) * 64; }

    // ---- one-time weight staging into resident LDS (plain loads) ----
    if (isZR) {
        const float* Um = Up + (size_t)(iA * 3 + gA) * DD * HH + col0;
        const float* Wm = Wp + (size_t)(iA * 3 + gA) * HH * HH + col0;
        for (int u = tid; u < 4096; u += TPB) {      // u = k*8 + cc
            int k = u >> 3, cc = u & 7;
            const float* ur = Um + (size_t)k * HH + cc;
            *(float4*)&lds[u * 4] = make_float4(ur[0], ur[8], ur[16], ur[24]);
            const float* wr = Wm + (size_t)k * HH + cc;
            *(float4*)&lds[16384 + u * 4] = make_float4(wr[0], wr[8], wr[16], wr[24]);
        }
    } else {
        const float* Mm = isHU ? (Up + (size_t)(iA * 3 + 2) * DD * HH + col0)
                               : (Wp + (size_t)(iB * 3 + 2) * HH * HH + col0B);
        for (int u = tid; u < 8192; u += TPB) {      // u = k*16 + q
            int k = u >> 4, q = u & 15;
            const float* mr = Mm + (size_t)k * HH + q;
            *(float4*)&lds[u * 4] = make_float4(mr[0], mr[16], mr[32], mr[48]);
        }
    }
    if (tid == 0) s_dead = 0;
    __syncthreads();

    if (isZR) {
        float* dst = (gA == 0 ? zbuf : rbuf) + (size_t)iA * HB;
        int* cb_up = (iA > 0) ? CNT(flags, iA - 1, 3) : nullptr;
        int* cb_my = CNT(flags, iA, 3);
        int* c_my  = CNT(flags, iA, gA);
        for (int t = 0; t < TT; ++t) {
            float a0 = 0.f, a1 = 0.f, a2 = 0.f, a3 = 0.f;
            // --- U-side first (off the recurrence chain) ---
            if (iA == 0) {
                const float* urow = x + ((size_t)b * TT + t) * DD;
                #pragma unroll 8
                for (int g = 0; g < 128; ++g) {
                    float4 xi = *(const float4*)&urow[g * 4];
                    #pragma unroll
                    for (int j = 0; j < 4; ++j) {
                        float xv = (&xi.x)[j];
                        float4 wv = *(const float4*)&lds[((g * 4 + j) * 8 + c) * 4];
                        a0 = fmaf(xv, wv.x, a0); a1 = fmaf(xv, wv.y, a1);
                        a2 = fmaf(xv, wv.z, a2); a3 = fmaf(xv, wv.w, a3);
                    }
                }
            } else {
                if (tid == 0) {
                    poll1(&s_dead, cb_up, 8 * (t + 1));
                    __builtin_amdgcn_fence(__ATOMIC_ACQUIRE, "agent");
                }
                __syncthreads();
                const float* urow = state + (size_t)((iA - 1) * 2 + (t & 1)) * HB;
                #pragma unroll 8
                for (int g = 0; g < 128; ++g) {
                    float4 xi = *(const float4*)&urow[GIDX(g, b)];
                    #pragma unroll
                    for (int j = 0; j < 4; ++j) {
                        float xv = (&xi.x)[j];
                        float4 wv = *(const float4*)&lds[((g * 4 + j) * 8 + c) * 4];
                        a0 = fmaf(xv, wv.x, a0); a1 = fmaf(xv, wv.y, a1);
                        a2 = fmaf(xv, wv.z, a2); a3 = fmaf(xv, wv.w, a3);
                    }
                }
            }
            // --- W-side: prev state ready + gate-buffer overwrite ack ---
            if (tid == 0) {
                poll1(&s_dead, cb_my, 8 * t);
                __builtin_amdgcn_fence(__ATOMIC_ACQUIRE, "agent");
            }
            __syncthreads();
            const float* prow = state + (size_t)(iA * 2 + ((t + 1) & 1)) * HB;
            #pragma unroll 8
            for (int g = 0; g < 128; ++g) {
                float4 pi = *(const float4*)&prow[GIDX(g, b)];
                #pragma unroll
                for (int j = 0; j < 4; ++j) {
                    float pv = (&pi.x)[j];
                    float4 wv = *(const float4*)&lds[16384 + ((g * 4 + j) * 8 + c) * 4];
                    a0 = fmaf(pv, wv.x, a0); a1 = fmaf(pv, wv.y, a1);
                    a2 = fmaf(pv, wv.z, a2); a3 = fmaf(pv, wv.w, a3);
                }
            }
            pub_store(&dst[CIDX(col0 + c,      b)], 1.0f / (1.0f + __expf(-a0)));
            pub_store(&dst[CIDX(col0 + c +  8, b)], 1.0f / (1.0f + __expf(-a1)));
            pub_store(&dst[CIDX(col0 + c + 16, b)], 1.0f / (1.0f + __expf(-a2)));
            pub_store(&dst[CIDX(col0 + c + 24, b)], 1.0f / (1.0f + __expf(-a3)));
            wg_post(c_my);
        }
    } else if (isHU) {
        float* hu = hUbuf + (size_t)iA * HB;
        int* cb_up = (iA > 0) ? CNT(flags, iA - 1, 3) : nullptr;
        int* cb_my = CNT(flags, iA, 3);
        int* c_my  = CNT(flags, iA, 2);
        for (int t = 0; t < TT; ++t) {
            float a0 = 0.f, a1 = 0.f, a2 = 0.f, a3 = 0.f;
            float a4 = 0.f, a5 = 0.f, a6 = 0.f, a7 = 0.f;
            if (iA == 0) {
                const float* urow = x + ((size_t)b * TT + t) * DD;
                #pragma unroll 4
                for (int g = 0; g < 128; ++g) {
                    float4 xi = *(const float4*)&urow[g * 4];
                    #pragma unroll
                    for (int j = 0; j < 4; ++j) {
                        float xv = (&xi.x)[j];
                        float4 w0 = *(const float4*)&lds[((g * 4 + j) * 16 + c) * 4];
                        float4 w1 = *(const float4*)&lds[((g * 4 + j) * 16 + c + 8) * 4];
                        a0 = fmaf(xv, w0.x, a0); a1 = fmaf(xv, w0.y, a1);
                        a2 = fmaf(xv, w0.z, a2); a3 = fmaf(xv, w0.w, a3);
                        a4 = fmaf(xv, w1.x, a4); a5 = fmaf(xv, w1.y, a5);
                        a6 = fmaf(xv, w1.z, a6); a7 = fmaf(xv, w1.w, a7);
                    }
                }
            } else {
                if (tid == 0) {
                    poll1(&s_dead, cb_up, 8 * (t + 1));
                    __builtin_amdgcn_fence(__ATOMIC_ACQUIRE, "agent");
                }
                __syncthreads();
                const float* urow = state + (size_t)((iA - 1) * 2 + (t & 1)) * HB;
                #pragma unroll 4
                for (int g = 0; g < 128; ++g) {
                    float4 xi = *(const float4*)&urow[GIDX(g, b)];
                    #pragma unroll
                    for (int j = 0; j < 4; ++j) {
                        float xv = (&xi.x)[j];
                        float4 w0 = *(const float4*)&lds[((g * 4 + j) * 16 + c) * 4];
                        float4 w1 = *(const float4*)&lds[((g * 4 + j) * 16 + c + 8) * 4];
                        a0 = fmaf(xv, w0.x, a0); a1 = fmaf(xv, w0.y, a1);
                        a2 = fmaf(xv, w0.z, a2); a3 = fmaf(xv, w0.w, a3);
                        a4 = fmaf(xv, w1.x, a4); a5 = fmaf(xv, w1.y, a5);
                        a6 = fmaf(xv, w1.z, a6); a7 = fmaf(xv, w1.w, a7);
                    }
                }
            }
            // store-ack only (B consumed hU(t-1)); nothing read after -> no fence
            if (tid == 0) poll1(&s_dead, cb_my, 8 * t);
            __syncthreads();
            pub_store(&hu[CIDX(col0 + c,      b)], a0);
            pub_store(&hu[CIDX(col0 + c + 16, b)], a1);
            pub_store(&hu[CIDX(col0 + c + 32, b)], a2);
            pub_store(&hu[CIDX(col0 + c + 48, b)], a3);
            pub_store(&hu[CIDX(col0 + c +  8, b)], a4);
            pub_store(&hu[CIDX(col0 + c + 24, b)], a5);
            pub_store(&hu[CIDX(col0 + c + 40, b)], a6);
            pub_store(&hu[CIDX(col0 + c + 56, b)], a7);
            wg_post(c_my);
        }
    } else {
        const float* rrow = rbuf + (size_t)iB * HB;
        const float* hu   = hUbuf + (size_t)iB * HB;
        const float* zz   = zbuf + (size_t)iB * HB;
        int* c_my = CNT(flags, iB, 3);
        for (int t = 0; t < TT; ++t) {
            // r gates ready (implies prow complete: r waited CB(i)>=8t)
            if (tid == 0) {
                poll1(&s_dead, CNT(flags, iB, 1), 16 * (t + 1));
                __builtin_amdgcn_fence(__ATOMIC_ACQUIRE, "agent");
            }
            __syncthreads();
            const float* prow = state + (size_t)(iB * 2 + ((t + 1) & 1)) * HB;
            float a0 = 0.f, a1 = 0.f, a2 = 0.f, a3 = 0.f;
            float a4 = 0.f, a5 = 0.f, a6 = 0.f, a7 = 0.f;
            #pragma unroll 4
            for (int g = 0; g < 128; ++g) {
                float4 ri = *(const float4*)&rrow[GIDX(g, b)];
                float4 pi = *(const float4*)&prow[GIDX(g, b)];
                #pragma unroll
                for (int j = 0; j < 4; ++j) {
                    float rp = (&ri.x)[j] * (&pi.x)[j];
                    float4 w0 = *(const float4*)&lds[((g * 4 + j) * 16 + c) * 4];
                    float4 w1 = *(const float4*)&lds[((g * 4 + j) * 16 + c + 8) * 4];
                    a0 = fmaf(rp, w0.x, a0); a1 = fmaf(rp, w0.y, a1);
                    a2 = fmaf(rp, w0.z, a2); a3 = fmaf(rp, w0.w, a3);
                    a4 = fmaf(rp, w1.x, a4); a5 = fmaf(rp, w1.y, a5);
                    a6 = fmaf(rp, w1.z, a6); a7 = fmaf(rp, w1.w, a7);
                }
            }
            // Epilogue deps + downstream overwrite ack, lane-parallel polls.
            // z/hU of step t; readers of s_i(t-2) are A(i+1,t-2) -> (t-1) lvls.
            if (tid < 8) {
                int* cp = nullptr; int tgt = 0;
                if (tid == 0)      { cp = CNT(flags, iB, 0); tgt = 16 * (t + 1); }
                else if (tid == 1) { cp = CNT(flags, iB, 2); tgt =  8 * (t + 1); }
                else if (iB < LL - 1) {
                    if (tid == 2)      { cp = CNT(flags, iB + 1, 0); tgt = 16 * (t - 1); }
                    else if (tid == 3) { cp = CNT(flags, iB + 1, 1); tgt = 16 * (t - 1); }
                    else if (tid == 4) { cp = CNT(flags, iB + 1, 2); tgt =  8 * (t - 1); }
                }
                if (cp) poll1(&s_dead, cp, tgt);
            }
            if (tid < 64)   // wave 0 reconverged: all polls done -> one inv
                __builtin_amdgcn_fence(__ATOMIC_ACQUIRE, "agent");
            __syncthreads();
            float* stNew = state + (size_t)(iB * 2 + (t & 1)) * HB;
            float acc[8] = {a0, a1, a2, a3, a4, a5, a6, a7};
            const int coff[8] = {0, 16, 32, 48, 8, 24, 40, 56};
            #pragma unroll
            for (int j = 0; j < 8; ++j) {
                const int col = col0B + c + coff[j];
                float a2v = acc[j] + hu[CIDX(col, b)];
                float h   = tanhf(a2v);
                float zg  = zz[CIDX(col, b)];
                float pv  = prow[CIDX(col, b)];          // L1-hot (read in GEMV)
                float s   = zg * (pv - h) + h;           // (1-z)*h + z*prev
                pub_store(&stNew[CIDX(col, b)], s);
                if (iB == LL - 1)
                    out[((size_t)b * TT + t) * HH + col] = s;
            }
            wg_post(c_my);
        }
    }
}

extern "C" void kernel_launch(void* const* d_in, const int* in_sizes, int n_in,
                              void* d_out, int out_size, void* d_ws, size_t ws_size,
                              hipStream_t stream) {
    const float* x  = (const float*)d_in[0];  // [32,512,512]
    const float* Wp = (const float*)d_in[1];  // [4,3,512,512]
    const float* Up = (const float*)d_in[2];  // [4,3,512,512]
    float* out = (float*)d_out;
    float* ws  = (float*)d_ws;

    // Sentinel 1: workspace too small -> absmax ~8.5e37
    if (ws_size < WS_NEED_BYTES) {
        hipMemsetAsync(d_out, 0x7e, (size_t)out_size * sizeof(float), stream);
        return;
    }

    // Host-side zero of state (t=0 prev) and counters each call.
    // State is only written by IC-level atomic stores in-kernel, so host
    // memset keeps it free of dirty L2 aliases.
    hipMemsetAsync(ws, 0, (size_t)STATE_FLOATS * sizeof(float), stream);
    hipMemsetAsync(ws + DATA_FLOATS, 0, FLAGS_BYTES, stream);

    hipLaunchKernelGGL(gru_wave, dim3(NWG), dim3(TPB), LDS_BYTES, stream,
                       x, Wp, Up, out, ws);
    // Sentinel 2: launch rejected -> absmax ~3.4e38
    hipError_t err = hipGetLastError();
    if (err != hipSuccess)
        hipMemsetAsync(d_out, 0x7f, (size_t)out_size * sizeof(float), stream);
}

// Round 5
// 26564.883 us; speedup vs baseline: 2.1930x; 1.7968x over previous
//
#include <hip/hip_runtime.h>

// Problem sizes (fixed by reference)
#define BB 32
#define TT 512
#define DD 512
#define HH 512
#define LL 4
#define HB (HH * BB)           // 16384
#define NWG 192
#define TPB 256

// ws: data floats then flag/counter slots (memset to 0 by host each call)
#define STATE_FLOATS (LL * 2 * HB)              // 131072
#define GATE_FLOATS  (3 * LL * HB)              // 196608
#define DATA_FLOATS  (STATE_FLOATS + GATE_FLOATS)
#define FLAG_STRIDE  64                          // 256 B per counter slot
#define NFLAG        209                         // keep prior ws footprint
#define FLAGS_BYTES  ((unsigned long long)NFLAG * FLAG_STRIDE * 4ull)
#define WS_NEED_BYTES ((unsigned long long)DATA_FLOATS * 4ull + FLAGS_BYTES)
#define LDS_BYTES 131072       // 128 KB resident weights

// ---- R1's proven self-timed dataflow (29.2 ms) — UNCHANGED ----
// done_A[i]: +1 per A-WG (32 ZR + 8 hU = 40/layer) per completed step.
// done_B[i]: +1 per B-WG (8/layer) per completed step.
//   A(i,t): U-side needs done_B[i-1] >= 8(t+1)   (inp; i=0 reads x, no wait)
//           W-side + stores need done_B[i] >= 8t (prev ready + gate ack)
//   B(i,t): needs done_A[i] >= 40(t+1); stores need done_A[i+1] >= 40t
// The ONLY change vs R1 is the GEMV inner structure:
//   R1: thread = (b, c): 1 b-row x 4 cols per weight ds_read_b128 -> 4 fmaf
//       per LDS instr; 4096 ds_read_b128 per WG-GEMV on the shared LDS pipe
//       (~10-20us) — the measured 57us/step is LDS-issue-bound, not sync.
//   R5: thread = (bq, cq, ks): 4 b-rows x 4 cols per weight read -> 16 fmaf
//       per LDS instr; 1024 ds_read per WG-GEMV. k-split partials reduced
//       via __shfl_xor within lane quads/pairs (no scratch, no barrier).
#define DONE_A(f, i) ((f) + (i) * FLAG_STRIDE)
#define DONE_B(f, i) ((f) + (8 + (i)) * FLAG_STRIDE)
#define SPIN_CAP (1 << 22)     // ~1.5 s worst case, then free-run (no hang)

__device__ __forceinline__ void wg_wait(int* cnt, int target, int& dead) {
    if (threadIdx.x == 0 && !dead) {
        int spins = 0;
        while (__hip_atomic_load(cnt, __ATOMIC_RELAXED,
                                 __HIP_MEMORY_SCOPE_AGENT) < target) {
            __builtin_amdgcn_s_sleep(2);
            if (++spins > SPIN_CAP) { dead = 1; break; }
        }
        // acquire: invalidate L1/L2 so subsequent plain loads see IC data
        (void)__hip_atomic_load(cnt, __ATOMIC_ACQUIRE,
                                __HIP_MEMORY_SCOPE_AGENT);
    }
    __syncthreads();
}

__device__ __forceinline__ void wg_post(int* cnt) {
    asm volatile("" ::: "memory");
    __builtin_amdgcn_s_waitcnt(0);   // own stores ack'd at coherence point
    __syncthreads();                 // all threads drained
    if (threadIdx.x == 0)
        atomicAdd(cnt, 1);           // device-scope, IC-level
}

__device__ __forceinline__ void pub_store(float* p, float v) {
    __hip_atomic_store(p, v, __ATOMIC_RELAXED, __HIP_MEMORY_SCOPE_AGENT);
}
__device__ __forceinline__ float sigf(float v) {
    return 1.0f / (1.0f + __expf(-v));
}

// WG roles (logical wg 0..191), TPB=256. State/gate buffers b-major
// (slice[b*512+col]) exactly as R1.
//   wg   0..127: A z/r. grp=wg>>4: i=grp>>1, g=grp&1; 32 cols.
//       thread: ks=tid&3 (k-quarter, 128 k), cq=(tid>>2)&7, bq=tid>>5.
//       LDS: lds[(k*8+cq)*4 ..] = M[k][col0+cq*4 .. +3]; U at 0, W at 16384.
//   wg 128..159: A hU. i=(wg-128)>>3; 64 cols.
//       thread: ks=tid&1 (k-half, 256 k), cq=(tid>>1)&15, bq=tid>>5.
//       LDS: lds[(k*16+cq)*4 ..] = U2[k][col0+cq*4 .. +3].
//   wg 160..191: B. i=(wg-160)>>3; 64 cols; thread map as hU; LDS = W2.
// Weight LDS reads per wave: 32 distinct float4 (cq x ks) = 512 B -> 4-cycle
// LDS bandwidth floor per instr (counted as "conflict"; expected, benign).

__global__ __launch_bounds__(TPB) void gru_wave(
    const float* __restrict__ x,    // [B,T,D]
    const float* __restrict__ Wp,   // [L,3,H,H]
    const float* __restrict__ Up,   // [L,3,D,H]
    float* __restrict__ out,        // [B,T,H]
    float* __restrict__ ws)
{
    extern __shared__ float lds[];  // 32768 floats

    const int bid = blockIdx.x;
    const int wg  = (bid & 7) * 24 + (bid >> 3);   // XCD-contiguous logical id
    const int tid = threadIdx.x;

    float* state = ws;                         // [L][2][B][H]
    float* zbuf  = state + LL * 2 * HB;        // [L][B][H]
    float* rbuf  = zbuf + LL * HB;
    float* hUbuf = rbuf + LL * HB;
    int*   flags = (int*)(ws + DATA_FLOATS);

    const bool isZR = wg < 128;
    const bool isHU = (wg >= 128) && (wg < 160);

    int iA = 0, gA = 0, col0 = 0, iB = 0, col0B = 0;
    if (isZR) { int grp = wg >> 4; iA = grp >> 1; gA = grp & 1; col0 = (wg & 15) * 32; }
    else if (isHU) { int w2 = wg - 128; iA = w2 >> 3; col0 = (w2 & 7) * 64; }
    else { int w3 = wg - 160; iB = w3 >> 3; col0B = (w3 & 7) * 64; }

    // ---- one-time weight staging: straight row-major float4 copy ----
    if (isZR) {
        const float* Um = Up + (size_t)(iA * 3 + gA) * DD * HH + col0;
        const float* Wm = Wp + (size_t)(iA * 3 + gA) * HH * HH + col0;
        for (int u = tid; u < 4096; u += TPB) {      // u = k*8 + cq
            int k = u >> 3, cc = u & 7;
            *(float4*)&lds[u * 4]         = *(const float4*)&Um[(size_t)k * HH + cc * 4];
            *(float4*)&lds[16384 + u * 4] = *(const float4*)&Wm[(size_t)k * HH + cc * 4];
        }
    } else {
        const float* Mm = isHU ? (Up + (size_t)(iA * 3 + 2) * DD * HH + col0)
                               : (Wp + (size_t)(iB * 3 + 2) * HH * HH + col0B);
        for (int u = tid; u < 8192; u += TPB) {      // u = k*16 + cq
            int k = u >> 4, cc = u & 15;
            *(float4*)&lds[u * 4] = *(const float4*)&Mm[(size_t)k * HH + cc * 4];
        }
    }
    __syncthreads();

    int dead = 0;

    if (isZR) {
        const int ks = tid & 3, cq = (tid >> 2) & 7, bq = tid >> 5;
        const int colq = col0 + cq * 4;
        const int kb = ks * 128;                 // this thread's k-quarter
        float* dst = (gA == 0 ? zbuf : rbuf) + (size_t)iA * HB;
        int* cb_up = (iA > 0) ? DONE_B(flags, iA - 1) : nullptr;
        int* cb_my = DONE_B(flags, iA);
        int* c_my  = DONE_A(flags, iA);
        for (int t = 0; t < TT; ++t) {
            float acc[4][4] = {};
            // --- U-side first (off the recurrence chain) ---
            const float* u0;
            size_t ustride;
            if (iA == 0) { u0 = x + ((size_t)(bq * 4) * TT + t) * DD + kb; ustride = (size_t)TT * DD; }
            else {
                if (cb_up) wg_wait(cb_up, 8 * (t + 1), dead);
                u0 = state + (size_t)((iA - 1) * 2 + (t & 1)) * HB + (bq * 4) * HH + kb;
                ustride = HH;
            }
            {
                const float* r0 = u0, *r1 = u0 + ustride, *r2 = u0 + 2 * ustride, *r3 = u0 + 3 * ustride;
                #pragma unroll 2
                for (int kc = 0; kc < 32; ++kc) {
                    float4 x0 = *(const float4*)&r0[kc * 4];
                    float4 x1 = *(const float4*)&r1[kc * 4];
                    float4 x2 = *(const float4*)&r2[kc * 4];
                    float4 x3 = *(const float4*)&r3[kc * 4];
                    #pragma unroll
                    for (int j = 0; j < 4; ++j) {
                        float4 wv = *(const float4*)&lds[((kb + kc * 4 + j) * 8 + cq) * 4];
                        float e0 = (&x0.x)[j], e1 = (&x1.x)[j], e2 = (&x2.x)[j], e3 = (&x3.x)[j];
                        acc[0][0] = fmaf(e0, wv.x, acc[0][0]); acc[0][1] = fmaf(e0, wv.y, acc[0][1]);
                        acc[0][2] = fmaf(e0, wv.z, acc[0][2]); acc[0][3] = fmaf(e0, wv.w, acc[0][3]);
                        acc[1][0] = fmaf(e1, wv.x, acc[1][0]); acc[1][1] = fmaf(e1, wv.y, acc[1][1]);
                        acc[1][2] = fmaf(e1, wv.z, acc[1][2]); acc[1][3] = fmaf(e1, wv.w, acc[1][3]);
                        acc[2][0] = fmaf(e2, wv.x, acc[2][0]); acc[2][1] = fmaf(e2, wv.y, acc[2][1]);
                        acc[2][2] = fmaf(e2, wv.z, acc[2][2]); acc[2][3] = fmaf(e2, wv.w, acc[2][3]);
                        acc[3][0] = fmaf(e3, wv.x, acc[3][0]); acc[3][1] = fmaf(e3, wv.y, acc[3][1]);
                        acc[3][2] = fmaf(e3, wv.z, acc[3][2]); acc[3][3] = fmaf(e3, wv.w, acc[3][3]);
                    }
                }
            }
            // --- W-side: prev state ready + gate-buffer overwrite ack ---
            wg_wait(cb_my, 8 * t, dead);
            {
                const float* p0 = state + (size_t)(iA * 2 + ((t + 1) & 1)) * HB + (bq * 4) * HH + kb;
                const float* q0 = p0, *q1 = p0 + HH, *q2 = p0 + 2 * HH, *q3 = p0 + 3 * HH;
                #pragma unroll 2
                for (int kc = 0; kc < 32; ++kc) {
                    float4 x0 = *(const float4*)&q0[kc * 4];
                    float4 x1 = *(const float4*)&q1[kc * 4];
                    float4 x2 = *(const float4*)&q2[kc * 4];
                    float4 x3 = *(const float4*)&q3[kc * 4];
                    #pragma unroll
                    for (int j = 0; j < 4; ++j) {
                        float4 wv = *(const float4*)&lds[16384 + ((kb + kc * 4 + j) * 8 + cq) * 4];
                        float e0 = (&x0.x)[j], e1 = (&x1.x)[j], e2 = (&x2.x)[j], e3 = (&x3.x)[j];
                        acc[0][0] = fmaf(e0, wv.x, acc[0][0]); acc[0][1] = fmaf(e0, wv.y, acc[0][1]);
                        acc[0][2] = fmaf(e0, wv.z, acc[0][2]); acc[0][3] = fmaf(e0, wv.w, acc[0][3]);
                        acc[1][0] = fmaf(e1, wv.x, acc[1][0]); acc[1][1] = fmaf(e1, wv.y, acc[1][1]);
                        acc[1][2] = fmaf(e1, wv.z, acc[1][2]); acc[1][3] = fmaf(e1, wv.w, acc[1][3]);
                        acc[2][0] = fmaf(e2, wv.x, acc[2][0]); acc[2][1] = fmaf(e2, wv.y, acc[2][1]);
                        acc[2][2] = fmaf(e2, wv.z, acc[2][2]); acc[2][3] = fmaf(e2, wv.w, acc[2][3]);
                        acc[3][0] = fmaf(e3, wv.x, acc[3][0]); acc[3][1] = fmaf(e3, wv.y, acc[3][1]);
                        acc[3][2] = fmaf(e3, wv.z, acc[3][2]); acc[3][3] = fmaf(e3, wv.w, acc[3][3]);
                    }
                }
            }
            // reduce over ks (lane quads share (bq,cq)); then lane ks stores row ks
            #pragma unroll
            for (int i = 0; i < 4; ++i)
                #pragma unroll
                for (int j = 0; j < 4; ++j) {
                    float v = acc[i][j];
                    v += __shfl_xor(v, 1, 64);
                    v += __shfl_xor(v, 2, 64);
                    acc[i][j] = v;
                }
            float s0, s1, s2, s3;
            if      (ks == 0) { s0 = acc[0][0]; s1 = acc[0][1]; s2 = acc[0][2]; s3 = acc[0][3]; }
            else if (ks == 1) { s0 = acc[1][0]; s1 = acc[1][1]; s2 = acc[1][2]; s3 = acc[1][3]; }
            else if (ks == 2) { s0 = acc[2][0]; s1 = acc[2][1]; s2 = acc[2][2]; s3 = acc[2][3]; }
            else              { s0 = acc[3][0]; s1 = acc[3][1]; s2 = acc[3][2]; s3 = acc[3][3]; }
            float* drow = dst + (size_t)(bq * 4 + ks) * HH + colq;
            pub_store(&drow[0], sigf(s0));
            pub_store(&drow[1], sigf(s1));
            pub_store(&drow[2], sigf(s2));
            pub_store(&drow[3], sigf(s3));
            wg_post(c_my);
        }
    } else if (isHU) {
        const int ks = tid & 1, cq = (tid >> 1) & 15, bq = tid >> 5;
        const int colq = col0 + cq * 4;
        const int kb = ks * 256;                 // this thread's k-half
        float* hu = hUbuf + (size_t)iA * HB;
        int* cb_up = (iA > 0) ? DONE_B(flags, iA - 1) : nullptr;
        int* cb_my = DONE_B(flags, iA);
        int* c_my  = DONE_A(flags, iA);
        for (int t = 0; t < TT; ++t) {
            float acc[4][4] = {};
            const float* u0;
            size_t ustride;
            if (iA == 0) { u0 = x + ((size_t)(bq * 4) * TT + t) * DD + kb; ustride = (size_t)TT * DD; }
            else {
                if (cb_up) wg_wait(cb_up, 8 * (t + 1), dead);
                u0 = state + (size_t)((iA - 1) * 2 + (t & 1)) * HB + (bq * 4) * HH + kb;
                ustride = HH;
            }
            {
                const float* r0 = u0, *r1 = u0 + ustride, *r2 = u0 + 2 * ustride, *r3 = u0 + 3 * ustride;
                #pragma unroll 2
                for (int kc = 0; kc < 64; ++kc) {
                    float4 x0 = *(const float4*)&r0[kc * 4];
                    float4 x1 = *(const float4*)&r1[kc * 4];
                    float4 x2 = *(const float4*)&r2[kc * 4];
                    float4 x3 = *(const float4*)&r3[kc * 4];
                    #pragma unroll
                    for (int j = 0; j < 4; ++j) {
                        float4 wv = *(const float4*)&lds[((kb + kc * 4 + j) * 16 + cq) * 4];
                        float e0 = (&x0.x)[j], e1 = (&x1.x)[j], e2 = (&x2.x)[j], e3 = (&x3.x)[j];
                        acc[0][0] = fmaf(e0, wv.x, acc[0][0]); acc[0][1] = fmaf(e0, wv.y, acc[0][1]);
                        acc[0][2] = fmaf(e0, wv.z, acc[0][2]); acc[0][3] = fmaf(e0, wv.w, acc[0][3]);
                        acc[1][0] = fmaf(e1, wv.x, acc[1][0]); acc[1][1] = fmaf(e1, wv.y, acc[1][1]);
                        acc[1][2] = fmaf(e1, wv.z, acc[1][2]); acc[1][3] = fmaf(e1, wv.w, acc[1][3]);
                        acc[2][0] = fmaf(e2, wv.x, acc[2][0]); acc[2][1] = fmaf(e2, wv.y, acc[2][1]);
                        acc[2][2] = fmaf(e2, wv.z, acc[2][2]); acc[2][3] = fmaf(e2, wv.w, acc[2][3]);
                        acc[3][0] = fmaf(e3, wv.x, acc[3][0]); acc[3][1] = fmaf(e3, wv.y, acc[3][1]);
                        acc[3][2] = fmaf(e3, wv.z, acc[3][2]); acc[3][3] = fmaf(e3, wv.w, acc[3][3]);
                    }
                }
            }
            // store-ack (B consumed hU(t-1)); then reduce over k-halves
            wg_wait(cb_my, 8 * t, dead);
            #pragma unroll
            for (int i = 0; i < 4; ++i)
                #pragma unroll
                for (int j = 0; j < 4; ++j) {
                    float v = acc[i][j];
                    v += __shfl_xor(v, 1, 64);
                    acc[i][j] = v;
                }
            float r0v[4], r1v[4];
            if (ks == 0) {
                r0v[0]=acc[0][0]; r0v[1]=acc[0][1]; r0v[2]=acc[0][2]; r0v[3]=acc[0][3];
                r1v[0]=acc[1][0]; r1v[1]=acc[1][1]; r1v[2]=acc[1][2]; r1v[3]=acc[1][3];
            } else {
                r0v[0]=acc[2][0]; r0v[1]=acc[2][1]; r0v[2]=acc[2][2]; r0v[3]=acc[2][3];
                r1v[0]=acc[3][0]; r1v[1]=acc[3][1]; r1v[2]=acc[3][2]; r1v[3]=acc[3][3];
            }
            const int b0 = bq * 4 + ks * 2;
            float* h0 = hu + (size_t)b0 * HH + colq;
            float* h1 = hu + (size_t)(b0 + 1) * HH + colq;
            pub_store(&h0[0], r0v[0]); pub_store(&h0[1], r0v[1]);
            pub_store(&h0[2], r0v[2]); pub_store(&h0[3], r0v[3]);
            pub_store(&h1[0], r1v[0]); pub_store(&h1[1], r1v[1]);
            pub_store(&h1[2], r1v[2]); pub_store(&h1[3], r1v[3]);
            wg_post(c_my);
        }
    } else {
        const int ks = tid & 1, cq = (tid >> 1) & 15, bq = tid >> 5;
        const int colq = col0B + cq * 4;
        const int kb = ks * 256;                 // this thread's k-half
        const float* rbase = rbuf + (size_t)iB * HB;
        const float* hu    = hUbuf + (size_t)iB * HB;
        const float* zz    = zbuf + (size_t)iB * HB;
        int* c_my = DONE_B(flags, iB);
        for (int t = 0; t < TT; ++t) {
            // all gates of step t ready (z, r, hU) — implies prow complete
            wg_wait(DONE_A(flags, iB), 40 * (t + 1), dead);
            const float* prow = state + (size_t)(iB * 2 + ((t + 1) & 1)) * HB;
            float acc[4][4] = {};
            {
                const float* rr = rbase + (size_t)(bq * 4) * HH + kb;
                const float* pp = prow + (size_t)(bq * 4) * HH + kb;
                #pragma unroll 2
                for (int kc = 0; kc < 64; ++kc) {
                    float4 ra = *(const float4*)&rr[kc * 4];
                    float4 rb = *(const float4*)&rr[HH + kc * 4];
                    float4 rc = *(const float4*)&rr[2 * HH + kc * 4];
                    float4 rd = *(const float4*)&rr[3 * HH + kc * 4];
                    float4 pa = *(const float4*)&pp[kc * 4];
                    float4 pb = *(const float4*)&pp[HH + kc * 4];
                    float4 pc = *(const float4*)&pp[2 * HH + kc * 4];
                    float4 pd = *(const float4*)&pp[3 * HH + kc * 4];
                    #pragma unroll
                    for (int j = 0; j < 4; ++j) {
                        float4 wv = *(const float4*)&lds[((kb + kc * 4 + j) * 16 + cq) * 4];
                        float e0 = (&ra.x)[j] * (&pa.x)[j];
                        float e1 = (&rb.x)[j] * (&pb.x)[j];
                        float e2 = (&rc.x)[j] * (&pc.x)[j];
                        float e3 = (&rd.x)[j] * (&pd.x)[j];
                        acc[0][0] = fmaf(e0, wv.x, acc[0][0]); acc[0][1] = fmaf(e0, wv.y, acc[0][1]);
                        acc[0][2] = fmaf(e0, wv.z, acc[0][2]); acc[0][3] = fmaf(e0, wv.w, acc[0][3]);
                        acc[1][0] = fmaf(e1, wv.x, acc[1][0]); acc[1][1] = fmaf(e1, wv.y, acc[1][1]);
                        acc[1][2] = fmaf(e1, wv.z, acc[1][2]); acc[1][3] = fmaf(e1, wv.w, acc[1][3]);
                        acc[2][0] = fmaf(e2, wv.x, acc[2][0]); acc[2][1] = fmaf(e2, wv.y, acc[2][1]);
                        acc[2][2] = fmaf(e2, wv.z, acc[2][2]); acc[2][3] = fmaf(e2, wv.w, acc[2][3]);
                        acc[3][0] = fmaf(e3, wv.x, acc[3][0]); acc[3][1] = fmaf(e3, wv.y, acc[3][1]);
                        acc[3][2] = fmaf(e3, wv.z, acc[3][2]); acc[3][3] = fmaf(e3, wv.w, acc[3][3]);
                    }
                }
            }
            // state(t-2) slot overwrite-ack: downstream A(i+1,t-1) done
            if (iB < 3) wg_wait(DONE_A(flags, iB + 1), 40 * t, dead);
            #pragma unroll
            for (int i = 0; i < 4; ++i)
                #pragma unroll
                for (int j = 0; j < 4; ++j) {
                    float v = acc[i][j];
                    v += __shfl_xor(v, 1, 64);
                    acc[i][j] = v;
                }
            float r0v[4], r1v[4];
            if (ks == 0) {
                r0v[0]=acc[0][0]; r0v[1]=acc[0][1]; r0v[2]=acc[0][2]; r0v[3]=acc[0][3];
                r1v[0]=acc[1][0]; r1v[1]=acc[1][1]; r1v[2]=acc[1][2]; r1v[3]=acc[1][3];
            } else {
                r0v[0]=acc[2][0]; r0v[1]=acc[2][1]; r0v[2]=acc[2][2]; r0v[3]=acc[2][3];
                r1v[0]=acc[3][0]; r1v[1]=acc[3][1]; r1v[2]=acc[3][2]; r1v[3]=acc[3][3];
            }
            float* stNew = state + (size_t)(iB * 2 + (t & 1)) * HB;
            const int b0 = bq * 4 + ks * 2;
            #pragma unroll
            for (int ii = 0; ii < 2; ++ii) {
                const int b = b0 + ii;
                float4 hu4 = *(const float4*)&hu[(size_t)b * HH + colq];
                float4 zz4 = *(const float4*)&zz[(size_t)b * HH + colq];
                float4 pv4 = *(const float4*)&prow[(size_t)b * HH + colq];
                float* av = ii ? r1v : r0v;
                float4 o4;
                #pragma unroll
                for (int j = 0; j < 4; ++j) {
                    float h  = tanhf(av[j] + (&hu4.x)[j]);
                    float zg = (&zz4.x)[j];
                    float s  = zg * ((&pv4.x)[j] - h) + h;   // (1-z)*h + z*prev
                    pub_store(&stNew[(size_t)b * HH + colq + j], s);
                    (&o4.x)[j] = s;
                }
                if (iB == LL - 1)
                    *(float4*)&out[((size_t)b * TT + t) * HH + colq] = o4;
            }
            wg_post(c_my);
        }
    }
}

extern "C" void kernel_launch(void* const* d_in, const int* in_sizes, int n_in,
                              void* d_out, int out_size, void* d_ws, size_t ws_size,
                              hipStream_t stream) {
    const float* x  = (const float*)d_in[0];  // [32,512,512]
    const float* Wp = (const float*)d_in[1];  // [4,3,512,512]
    const float* Up = (const float*)d_in[2];  // [4,3,512,512]
    float* out = (float*)d_out;
    float* ws  = (float*)d_ws;

    // Sentinel 1: workspace too small -> absmax ~8.5e37
    if (ws_size < WS_NEED_BYTES) {
        hipMemsetAsync(d_out, 0x7e, (size_t)out_size * sizeof(float), stream);
        return;
    }

    // Host-side zero of state (t=0 prev) and counters each call (R1-proven).
    hipMemsetAsync(ws, 0, (size_t)STATE_FLOATS * sizeof(float), stream);
    hipMemsetAsync(ws + DATA_FLOATS, 0, FLAGS_BYTES, stream);

    hipLaunchKernelGGL(gru_wave, dim3(NWG), dim3(TPB), LDS_BYTES, stream,
                       x, Wp, Up, out, ws);
    // Sentinel 2: launch rejected -> absmax ~3.4e38
    hipError_t err = hipGetLastError();
    if (err != hipSuccess)
        hipMemsetAsync(d_out, 0x7f, (size_t)out_size * sizeof(float), stream);
}

// Round 6
// 14075.848 us; speedup vs baseline: 4.1387x; 1.8873x over previous
//
#include <hip/hip_runtime.h>

// Problem sizes (fixed by reference)
#define BB 32
#define TT 512
#define DD 512
#define HH 512
#define LL 4
#define HB (HH * BB)           // 16384
#define NWG 192
#define TPB 256

// ws: data floats then flag/counter slots (memset to 0 by host each call)
#define STATE_FLOATS (LL * 2 * HB)              // 131072
#define GATE_FLOATS  (3 * LL * HB)              // 196608
#define DATA_FLOATS  (STATE_FLOATS + GATE_FLOATS)
#define FLAG_STRIDE  64                          // 256 B per counter slot
#define NFLAG        209                         // keep prior ws footprint
#define FLAGS_BYTES  ((unsigned long long)NFLAG * FLAG_STRIDE * 4ull)
#define WS_NEED_BYTES ((unsigned long long)DATA_FLOATS * 4ull + FLAGS_BYTES)

// LDS: 128 KB resident weights + double-buffered input chunks.
// Chunk = 64 k x 32 b staged once (coalesced) instead of each (b,k) element
// being re-read from IC by 8 cq-threads (R5's 512KB/WG/GEMV latency-exposed
// stream was the dominant term). Row pitch 68 floats de-conflicts ds_writes.
#define KC    64                      // k per chunk
#define NCH   (HH / KC)               // 8 chunks per GEMV
#define IBR   68                      // input buffer row pitch (floats)
#define IBF   (BB * IBR)              // 2176 floats per chunk buffer
#define WLDS  32768                   // weight region (floats)
#define LDS_BYTES ((WLDS + 2 * IBF) * 4)   // 148480 <= 163840

// ---- R1/R5's proven self-timed dataflow — UNCHANGED ----
// done_A[i]: +1 per A-WG (32 ZR + 8 hU = 40/layer) per completed step.
// done_B[i]: +1 per B-WG (8/layer) per completed step.
//   A(i,t): U-side needs done_B[i-1] >= 8(t+1)   (inp; i=0 reads x, no wait)
//           W-side + stores need done_B[i] >= 8t (prev ready + gate ack)
//   B(i,t): needs done_A[i] >= 40(t+1); stores need done_A[i+1] >= 40t
#define DONE_A(f, i) ((f) + (i) * FLAG_STRIDE)
#define DONE_B(f, i) ((f) + (8 + (i)) * FLAG_STRIDE)
#define SPIN_CAP (1 << 22)     // ~1.5 s worst case, then free-run (no hang)

__device__ __forceinline__ void wg_wait(int* cnt, int target, int& dead) {
    if (threadIdx.x == 0 && !dead) {
        int spins = 0;
        while (__hip_atomic_load(cnt, __ATOMIC_RELAXED,
                                 __HIP_MEMORY_SCOPE_AGENT) < target) {
            __builtin_amdgcn_s_sleep(2);
            if (++spins > SPIN_CAP) { dead = 1; break; }
        }
        // acquire: invalidate L1/L2 so subsequent plain loads see IC data
        (void)__hip_atomic_load(cnt, __ATOMIC_ACQUIRE,
                                __HIP_MEMORY_SCOPE_AGENT);
    }
    __syncthreads();
}

__device__ __forceinline__ void wg_post(int* cnt) {
    asm volatile("" ::: "memory");
    __builtin_amdgcn_s_waitcnt(0);   // own stores ack'd at coherence point
    __syncthreads();                 // all threads drained
    if (threadIdx.x == 0)
        atomicAdd(cnt, 1);           // device-scope, IC-level
}

__device__ __forceinline__ void pub_store(float* p, float v) {
    __hip_atomic_store(p, v, __ATOMIC_RELAXED, __HIP_MEMORY_SCOPE_AGENT);
}
__device__ __forceinline__ float sigf(float v) {
    return 1.0f / (1.0f + __expf(-v));
}

// 16-fmaf register tile (4 rows x 4 cols) on one weight float4
#define FMA16(WV, E0, E1, E2, E3)                                           \
    acc[0][0] = fmaf(E0, WV.x, acc[0][0]); acc[0][1] = fmaf(E0, WV.y, acc[0][1]); \
    acc[0][2] = fmaf(E0, WV.z, acc[0][2]); acc[0][3] = fmaf(E0, WV.w, acc[0][3]); \
    acc[1][0] = fmaf(E1, WV.x, acc[1][0]); acc[1][1] = fmaf(E1, WV.y, acc[1][1]); \
    acc[1][2] = fmaf(E1, WV.z, acc[1][2]); acc[1][3] = fmaf(E1, WV.w, acc[1][3]); \
    acc[2][0] = fmaf(E2, WV.x, acc[2][0]); acc[2][1] = fmaf(E2, WV.y, acc[2][1]); \
    acc[2][2] = fmaf(E2, WV.z, acc[2][2]); acc[2][3] = fmaf(E2, WV.w, acc[2][3]); \
    acc[3][0] = fmaf(E3, WV.x, acc[3][0]); acc[3][1] = fmaf(E3, WV.y, acc[3][1]); \
    acc[3][2] = fmaf(E3, WV.z, acc[3][2]); acc[3][3] = fmaf(E3, WV.w, acc[3][3])

// WG roles (logical wg 0..191), TPB=256. Buffers b-major (slice[b*512+col]).
//   wg   0..127: A z/r. grp=wg>>4: i=grp>>1, g=grp&1; 32 cols.
//       compute map: ksc=tid&3 (16 k of each 64-chunk), cq=(tid>>2)&7, bq=tid>>5
//       weights: lds[(k*8+cq)*4..] = M[k][col0+cq*4..+3]; U at 0, W at 16384
//   wg 128..159: A hU. i=(wg-128)>>3; 64 cols.
//       compute map: ks2=tid&1 (32 k/chunk), cq=(tid>>1)&15, bq=tid>>5
//       weights: lds[(k*16+cq)*4..] = U2[k][col0+cq*4..+3]
//   wg 160..191: B. i=(wg-160)>>3; 64 cols; map as hU; LDS = W2; staged input
//       is the product r*p (computed by staging threads; bitwise same math).
//   staging map (all roles): sb=tid>>4 (rows sb, sb+16), sk=tid&15 (float4).

__global__ __launch_bounds__(TPB) void gru_wave(
    const float* __restrict__ x,    // [B,T,D]
    const float* __restrict__ Wp,   // [L,3,H,H]
    const float* __restrict__ Up,   // [L,3,D,H]
    float* __restrict__ out,        // [B,T,H]
    float* __restrict__ ws)
{
    extern __shared__ float lds[];

    const int bid = blockIdx.x;
    const int wg  = (bid & 7) * 24 + (bid >> 3);   // XCD-contiguous logical id
    const int tid = threadIdx.x;
    const int sb  = tid >> 4;          // staging row (and row+16)
    const int sk  = tid & 15;          // staging float4 within 64-k row chunk

    float* state = ws;                         // [L][2][B][H]
    float* zbuf  = state + LL * 2 * HB;        // [L][B][H]
    float* rbuf  = zbuf + LL * HB;
    float* hUbuf = rbuf + LL * HB;
    int*   flags = (int*)(ws + DATA_FLOATS);

    float* ib0 = lds + WLDS;
    float* ib1 = ib0 + IBF;

    const bool isZR = wg < 128;
    const bool isHU = (wg >= 128) && (wg < 160);

    int iA = 0, gA = 0, col0 = 0, iB = 0, col0B = 0;
    if (isZR) { int grp = wg >> 4; iA = grp >> 1; gA = grp & 1; col0 = (wg & 15) * 32; }
    else if (isHU) { int w2 = wg - 128; iA = w2 >> 3; col0 = (w2 & 7) * 64; }
    else { int w3 = wg - 160; iB = w3 >> 3; col0B = (w3 & 7) * 64; }

    // ---- one-time weight staging: straight row-major float4 copy ----
    if (isZR) {
        const float* Um = Up + (size_t)(iA * 3 + gA) * DD * HH + col0;
        const float* Wm = Wp + (size_t)(iA * 3 + gA) * HH * HH + col0;
        for (int u = tid; u < 4096; u += TPB) {      // u = k*8 + cq
            int k = u >> 3, cc = u & 7;
            *(float4*)&lds[u * 4]         = *(const float4*)&Um[(size_t)k * HH + cc * 4];
            *(float4*)&lds[16384 + u * 4] = *(const float4*)&Wm[(size_t)k * HH + cc * 4];
        }
    } else {
        const float* Mm = isHU ? (Up + (size_t)(iA * 3 + 2) * DD * HH + col0)
                               : (Wp + (size_t)(iB * 3 + 2) * HH * HH + col0B);
        for (int u = tid; u < 8192; u += TPB) {      // u = k*16 + cq
            int k = u >> 4, cc = u & 15;
            *(float4*)&lds[u * 4] = *(const float4*)&Mm[(size_t)k * HH + cc * 4];
        }
    }
    __syncthreads();

    int dead = 0;

    if (isZR) {
        const int ksc = tid & 3, cq = (tid >> 2) & 7, bq = tid >> 5;
        const int colq = col0 + cq * 4;
        float* dst = (gA == 0 ? zbuf : rbuf) + (size_t)iA * HB;
        int* cb_up = (iA > 0) ? DONE_B(flags, iA - 1) : nullptr;
        int* cb_my = DONE_B(flags, iA);
        int* c_my  = DONE_A(flags, iA);
        for (int t = 0; t < TT; ++t) {
            float acc[4][4] = {};
            // ================= U-half (staged) =================
            if (cb_up) wg_wait(cb_up, 8 * (t + 1), dead);
            {
                const float* src; size_t rstr;
                if (iA == 0) {
                    src = x + (size_t)sb * TT * DD + (size_t)t * DD + sk * 4;
                    rstr = (size_t)16 * TT * DD;
                } else {
                    src = state + (size_t)((iA - 1) * 2 + (t & 1)) * HB + sb * HH + sk * 4;
                    rstr = (size_t)16 * HH;
                }
                float4 g0 = *(const float4*)&src[0];
                float4 g1 = *(const float4*)&src[rstr];
                src += KC;
                *(float4*)&ib0[sb * IBR + sk * 4]        = g0;
                *(float4*)&ib0[(sb + 16) * IBR + sk * 4] = g1;
                g0 = *(const float4*)&src[0]; g1 = *(const float4*)&src[rstr]; src += KC;
                __syncthreads();
                float *rb = ib0, *nb = ib1;
                const float* wp0 = lds + (ksc * 16 * 8 + cq) * 4;
                for (int c = 0; c < NCH; ++c) {
                    const float* r0 = rb + (bq * 4 + 0) * IBR + ksc * 16;
                    const float* r1 = rb + (bq * 4 + 1) * IBR + ksc * 16;
                    const float* r2 = rb + (bq * 4 + 2) * IBR + ksc * 16;
                    const float* r3 = rb + (bq * 4 + 3) * IBR + ksc * 16;
                    const float* wp = wp0 + c * (KC * 8 * 4);
                    #pragma unroll
                    for (int kk = 0; kk < 4; ++kk) {
                        float4 x0 = *(const float4*)&r0[kk * 4];
                        float4 x1 = *(const float4*)&r1[kk * 4];
                        float4 x2 = *(const float4*)&r2[kk * 4];
                        float4 x3 = *(const float4*)&r3[kk * 4];
                        #pragma unroll
                        for (int j = 0; j < 4; ++j) {
                            float4 wv = *(const float4*)&wp[(kk * 4 + j) * 32];
                            FMA16(wv, (&x0.x)[j], (&x1.x)[j], (&x2.x)[j], (&x3.x)[j]);
                        }
                    }
                    if (c < NCH - 1) {
                        *(float4*)&nb[sb * IBR + sk * 4]        = g0;
                        *(float4*)&nb[(sb + 16) * IBR + sk * 4] = g1;
                        if (c < NCH - 2) {
                            g0 = *(const float4*)&src[0];
                            g1 = *(const float4*)&src[rstr];
                            src += KC;
                        }
                    }
                    __syncthreads();
                    float* tp = rb; rb = nb; nb = tp;
                }
            }
            // ================= W-half (staged) =================
            wg_wait(cb_my, 8 * t, dead);
            {
                const float* src = state + (size_t)(iA * 2 + ((t + 1) & 1)) * HB
                                 + sb * HH + sk * 4;
                const size_t rstr = (size_t)16 * HH;
                float4 g0 = *(const float4*)&src[0];
                float4 g1 = *(const float4*)&src[rstr];
                src += KC;
                *(float4*)&ib0[sb * IBR + sk * 4]        = g0;
                *(float4*)&ib0[(sb + 16) * IBR + sk * 4] = g1;
                g0 = *(const float4*)&src[0]; g1 = *(const float4*)&src[rstr]; src += KC;
                __syncthreads();
                float *rb = ib0, *nb = ib1;
                const float* wp0 = lds + 16384 + (ksc * 16 * 8 + cq) * 4;
                for (int c = 0; c < NCH; ++c) {
                    const float* r0 = rb + (bq * 4 + 0) * IBR + ksc * 16;
                    const float* r1 = rb + (bq * 4 + 1) * IBR + ksc * 16;
                    const float* r2 = rb + (bq * 4 + 2) * IBR + ksc * 16;
                    const float* r3 = rb + (bq * 4 + 3) * IBR + ksc * 16;
                    const float* wp = wp0 + c * (KC * 8 * 4);
                    #pragma unroll
                    for (int kk = 0; kk < 4; ++kk) {
                        float4 x0 = *(const float4*)&r0[kk * 4];
                        float4 x1 = *(const float4*)&r1[kk * 4];
                        float4 x2 = *(const float4*)&r2[kk * 4];
                        float4 x3 = *(const float4*)&r3[kk * 4];
                        #pragma unroll
                        for (int j = 0; j < 4; ++j) {
                            float4 wv = *(const float4*)&wp[(kk * 4 + j) * 32];
                            FMA16(wv, (&x0.x)[j], (&x1.x)[j], (&x2.x)[j], (&x3.x)[j]);
                        }
                    }
                    if (c < NCH - 1) {
                        *(float4*)&nb[sb * IBR + sk * 4]        = g0;
                        *(float4*)&nb[(sb + 16) * IBR + sk * 4] = g1;
                        if (c < NCH - 2) {
                            g0 = *(const float4*)&src[0];
                            g1 = *(const float4*)&src[rstr];
                            src += KC;
                        }
                    }
                    __syncthreads();
                    float* tp = rb; rb = nb; nb = tp;
                }
            }
            // reduce over ksc (lane quads share (bq,cq)); lane ksc stores row ksc
            #pragma unroll
            for (int i = 0; i < 4; ++i)
                #pragma unroll
                for (int j = 0; j < 4; ++j) {
                    float v = acc[i][j];
                    v += __shfl_xor(v, 1, 64);
                    v += __shfl_xor(v, 2, 64);
                    acc[i][j] = v;
                }
            float s0, s1, s2, s3;
            if      (ksc == 0) { s0 = acc[0][0]; s1 = acc[0][1]; s2 = acc[0][2]; s3 = acc[0][3]; }
            else if (ksc == 1) { s0 = acc[1][0]; s1 = acc[1][1]; s2 = acc[1][2]; s3 = acc[1][3]; }
            else if (ksc == 2) { s0 = acc[2][0]; s1 = acc[2][1]; s2 = acc[2][2]; s3 = acc[2][3]; }
            else               { s0 = acc[3][0]; s1 = acc[3][1]; s2 = acc[3][2]; s3 = acc[3][3]; }
            float* drow = dst + (size_t)(bq * 4 + ksc) * HH + colq;
            pub_store(&drow[0], sigf(s0));
            pub_store(&drow[1], sigf(s1));
            pub_store(&drow[2], sigf(s2));
            pub_store(&drow[3], sigf(s3));
            wg_post(c_my);
        }
    } else if (isHU) {
        const int ks2 = tid & 1, cq = (tid >> 1) & 15, bq = tid >> 5;
        const int colq = col0 + cq * 4;
        float* hu = hUbuf + (size_t)iA * HB;
        int* cb_up = (iA > 0) ? DONE_B(flags, iA - 1) : nullptr;
        int* cb_my = DONE_B(flags, iA);
        int* c_my  = DONE_A(flags, iA);
        for (int t = 0; t < TT; ++t) {
            float acc[4][4] = {};
            if (cb_up) wg_wait(cb_up, 8 * (t + 1), dead);
            {
                const float* src; size_t rstr;
                if (iA == 0) {
                    src = x + (size_t)sb * TT * DD + (size_t)t * DD + sk * 4;
                    rstr = (size_t)16 * TT * DD;
                } else {
                    src = state + (size_t)((iA - 1) * 2 + (t & 1)) * HB + sb * HH + sk * 4;
                    rstr = (size_t)16 * HH;
                }
                float4 g0 = *(const float4*)&src[0];
                float4 g1 = *(const float4*)&src[rstr];
                src += KC;
                *(float4*)&ib0[sb * IBR + sk * 4]        = g0;
                *(float4*)&ib0[(sb + 16) * IBR + sk * 4] = g1;
                g0 = *(const float4*)&src[0]; g1 = *(const float4*)&src[rstr]; src += KC;
                __syncthreads();
                float *rb = ib0, *nb = ib1;
                const float* wp0 = lds + (ks2 * 32 * 16 + cq) * 4;
                for (int c = 0; c < NCH; ++c) {
                    const float* r0 = rb + (bq * 4 + 0) * IBR + ks2 * 32;
                    const float* r1 = rb + (bq * 4 + 1) * IBR + ks2 * 32;
                    const float* r2 = rb + (bq * 4 + 2) * IBR + ks2 * 32;
                    const float* r3 = rb + (bq * 4 + 3) * IBR + ks2 * 32;
                    const float* wp = wp0 + c * (KC * 16 * 4);
                    #pragma unroll
                    for (int kk = 0; kk < 8; ++kk) {
                        float4 x0 = *(const float4*)&r0[kk * 4];
                        float4 x1 = *(const float4*)&r1[kk * 4];
                        float4 x2 = *(const float4*)&r2[kk * 4];
                        float4 x3 = *(const float4*)&r3[kk * 4];
                        #pragma unroll
                        for (int j = 0; j < 4; ++j) {
                            float4 wv = *(const float4*)&wp[(kk * 4 + j) * 64];
                            FMA16(wv, (&x0.x)[j], (&x1.x)[j], (&x2.x)[j], (&x3.x)[j]);
                        }
                    }
                    if (c < NCH - 1) {
                        *(float4*)&nb[sb * IBR + sk * 4]        = g0;
                        *(float4*)&nb[(sb + 16) * IBR + sk * 4] = g1;
                        if (c < NCH - 2) {
                            g0 = *(const float4*)&src[0];
                            g1 = *(const float4*)&src[rstr];
                            src += KC;
                        }
                    }
                    __syncthreads();
                    float* tp = rb; rb = nb; nb = tp;
                }
            }
            // store-ack (B consumed hU(t-1)); then reduce over k-halves
            wg_wait(cb_my, 8 * t, dead);
            #pragma unroll
            for (int i = 0; i < 4; ++i)
                #pragma unroll
                for (int j = 0; j < 4; ++j) {
                    float v = acc[i][j];
                    v += __shfl_xor(v, 1, 64);
                    acc[i][j] = v;
                }
            float r0v[4], r1v[4];
            if (ks2 == 0) {
                r0v[0]=acc[0][0]; r0v[1]=acc[0][1]; r0v[2]=acc[0][2]; r0v[3]=acc[0][3];
                r1v[0]=acc[1][0]; r1v[1]=acc[1][1]; r1v[2]=acc[1][2]; r1v[3]=acc[1][3];
            } else {
                r0v[0]=acc[2][0]; r0v[1]=acc[2][1]; r0v[2]=acc[2][2]; r0v[3]=acc[2][3];
                r1v[0]=acc[3][0]; r1v[1]=acc[3][1]; r1v[2]=acc[3][2]; r1v[3]=acc[3][3];
            }
            const int b0 = bq * 4 + ks2 * 2;
            float* h0 = hu + (size_t)b0 * HH + colq;
            float* h1 = hu + (size_t)(b0 + 1) * HH + colq;
            pub_store(&h0[0], r0v[0]); pub_store(&h0[1], r0v[1]);
            pub_store(&h0[2], r0v[2]); pub_store(&h0[3], r0v[3]);
            pub_store(&h1[0], r1v[0]); pub_store(&h1[1], r1v[1]);
            pub_store(&h1[2], r1v[2]); pub_store(&h1[3], r1v[3]);
            wg_post(c_my);
        }
    } else {
        const int ks2 = tid & 1, cq = (tid >> 1) & 15, bq = tid >> 5;
        const int colq = col0B + cq * 4;
        const float* rbase = rbuf + (size_t)iB * HB;
        const float* hu    = hUbuf + (size_t)iB * HB;
        const float* zz    = zbuf + (size_t)iB * HB;
        int* c_my = DONE_B(flags, iB);
        for (int t = 0; t < TT; ++t) {
            // all gates of step t ready (z, r, hU) — implies prow complete
            wg_wait(DONE_A(flags, iB), 40 * (t + 1), dead);
            const float* prow = state + (size_t)(iB * 2 + ((t + 1) & 1)) * HB;
            float acc[4][4] = {};
            {
                // staged product rp = r*p (computed at staging; same math order)
                const float* rs = rbase + (size_t)sb * HH + sk * 4;
                const float* ps = prow  + (size_t)sb * HH + sk * 4;
                const size_t rstr = (size_t)16 * HH;
                float4 g0r = *(const float4*)&rs[0],   g0p = *(const float4*)&ps[0];
                float4 g1r = *(const float4*)&rs[rstr], g1p = *(const float4*)&ps[rstr];
                rs += KC; ps += KC;
                *(float4*)&ib0[sb * IBR + sk * 4] =
                    make_float4(g0r.x * g0p.x, g0r.y * g0p.y, g0r.z * g0p.z, g0r.w * g0p.w);
                *(float4*)&ib0[(sb + 16) * IBR + sk * 4] =
                    make_float4(g1r.x * g1p.x, g1r.y * g1p.y, g1r.z * g1p.z, g1r.w * g1p.w);
                g0r = *(const float4*)&rs[0];   g0p = *(const float4*)&ps[0];
                g1r = *(const float4*)&rs[rstr]; g1p = *(const float4*)&ps[rstr];
                rs += KC; ps += KC;
                __syncthreads();
                float *rb = ib0, *nb = ib1;
                const float* wp0 = lds + (ks2 * 32 * 16 + cq) * 4;
                for (int c = 0; c < NCH; ++c) {
                    const float* r0 = rb + (bq * 4 + 0) * IBR + ks2 * 32;
                    const float* r1 = rb + (bq * 4 + 1) * IBR + ks2 * 32;
                    const float* r2 = rb + (bq * 4 + 2) * IBR + ks2 * 32;
                    const float* r3 = rb + (bq * 4 + 3) * IBR + ks2 * 32;
                    const float* wp = wp0 + c * (KC * 16 * 4);
                    #pragma unroll
                    for (int kk = 0; kk < 8; ++kk) {
                        float4 x0 = *(const float4*)&r0[kk * 4];
                        float4 x1 = *(const float4*)&r1[kk * 4];
                        float4 x2 = *(const float4*)&r2[kk * 4];
                        float4 x3 = *(const float4*)&r3[kk * 4];
                        #pragma unroll
                        for (int j = 0; j < 4; ++j) {
                            float4 wv = *(const float4*)&wp[(kk * 4 + j) * 64];
                            FMA16(wv, (&x0.x)[j], (&x1.x)[j], (&x2.x)[j], (&x3.x)[j]);
                        }
                    }
                    if (c < NCH - 1) {
                        *(float4*)&nb[sb * IBR + sk * 4] =
                            make_float4(g0r.x * g0p.x, g0r.y * g0p.y, g0r.z * g0p.z, g0r.w * g0p.w);
                        *(float4*)&nb[(sb + 16) * IBR + sk * 4] =
                            make_float4(g1r.x * g1p.x, g1r.y * g1p.y, g1r.z * g1p.z, g1r.w * g1p.w);
                        if (c < NCH - 2) {
                            g0r = *(const float4*)&rs[0];   g0p = *(const float4*)&ps[0];
                            g1r = *(const float4*)&rs[rstr]; g1p = *(const float4*)&ps[rstr];
                            rs += KC; ps += KC;
                        }
                    }
                    __syncthreads();
                    float* tp = rb; rb = nb; nb = tp;
                }
            }
            // state(t-2) slot overwrite-ack: downstream A(i+1,t-1) done
            if (iB < 3) wg_wait(DONE_A(flags, iB + 1), 40 * t, dead);
            #pragma unroll
            for (int i = 0; i < 4; ++i)
                #pragma unroll
                for (int j = 0; j < 4; ++j) {
                    float v = acc[i][j];
                    v += __shfl_xor(v, 1, 64);
                    acc[i][j] = v;
                }
            float r0v[4], r1v[4];
            if (ks2 == 0) {
                r0v[0]=acc[0][0]; r0v[1]=acc[0][1]; r0v[2]=acc[0][2]; r0v[3]=acc[0][3];
                r1v[0]=acc[1][0]; r1v[1]=acc[1][1]; r1v[2]=acc[1][2]; r1v[3]=acc[1][3];
            } else {
                r0v[0]=acc[2][0]; r0v[1]=acc[2][1]; r0v[2]=acc[2][2]; r0v[3]=acc[2][3];
                r1v[0]=acc[3][0]; r1v[1]=acc[3][1]; r1v[2]=acc[3][2]; r1v[3]=acc[3][3];
            }
            float* stNew = state + (size_t)(iB * 2 + (t & 1)) * HB;
            const int b0 = bq * 4 + ks2 * 2;
            #pragma unroll
            for (int ii = 0; ii < 2; ++ii) {
                const int b = b0 + ii;
                float4 hu4 = *(const float4*)&hu[(size_t)b * HH + colq];
                float4 zz4 = *(const float4*)&zz[(size_t)b * HH + colq];
                float4 pv4 = *(const float4*)&prow[(size_t)b * HH + colq];
                float* av = ii ? r1v : r0v;
                float4 o4;
                #pragma unroll
                for (int j = 0; j < 4; ++j) {
                    float h  = tanhf(av[j] + (&hu4.x)[j]);
                    float zg = (&zz4.x)[j];
                    float s  = zg * ((&pv4.x)[j] - h) + h;   // (1-z)*h + z*prev
                    pub_store(&stNew[(size_t)b * HH + colq + j], s);
                    (&o4.x)[j] = s;
                }
                if (iB == LL - 1)
                    *(float4*)&out[((size_t)b * TT + t) * HH + colq] = o4;
            }
            wg_post(c_my);
        }
    }
}

extern "C" void kernel_launch(void* const* d_in, const int* in_sizes, int n_in,
                              void* d_out, int out_size, void* d_ws, size_t ws_size,
                              hipStream_t stream) {
    const float* x  = (const float*)d_in[0];  // [32,512,512]
    const float* Wp = (const float*)d_in[1];  // [4,3,512,512]
    const float* Up = (const float*)d_in[2];  // [4,3,512,512]
    float* out = (float*)d_out;
    float* ws  = (float*)d_ws;

    // Sentinel 1: workspace too small -> absmax ~8.5e37
    if (ws_size < WS_NEED_BYTES) {
        hipMemsetAsync(d_out, 0x7e, (size_t)out_size * sizeof(float), stream);
        return;
    }

    // Host-side zero of state (t=0 prev) and counters each call (R1-proven).
    hipMemsetAsync(ws, 0, (size_t)STATE_FLOATS * sizeof(float), stream);
    hipMemsetAsync(ws + DATA_FLOATS, 0, FLAGS_BYTES, stream);

    hipLaunchKernelGGL(gru_wave, dim3(NWG), dim3(TPB), LDS_BYTES, stream,
                       x, Wp, Up, out, ws);
    // Sentinel 2: launch rejected -> absmax ~3.4e38
    hipError_t err = hipGetLastError();
    if (err != hipSuccess)
        hipMemsetAsync(d_out, 0x7f, (size_t)out_size * sizeof(float), stream);
}

// Round 7
// 12339.191 us; speedup vs baseline: 4.7212x; 1.1407x over previous
//
#include <hip/hip_runtime.h>

// Problem sizes (fixed by reference)
#define BB 32
#define TT 512
#define DD 512
#define HH 512
#define LL 4
#define HB (HH * BB)           // 16384
#define NWG 224                // 28 per XCD; 1 WG/CU (LDS-bound)
#define TPB 256

// ws: data floats then flag/counter slots (memset to 0 by host each call)
#define STATE_FLOATS (LL * 2 * HB)              // 131072
#define GATE_FLOATS  (3 * LL * HB)              // 196608
#define DATA_FLOATS  (STATE_FLOATS + GATE_FLOATS)
#define FLAG_STRIDE  64                          // 256 B per counter slot
#define NFLAG        209                         // keep prior ws footprint
#define FLAGS_BYTES  ((unsigned long long)NFLAG * FLAG_STRIDE * 4ull)
#define WS_NEED_BYTES ((unsigned long long)DATA_FLOATS * 4ull + FLAGS_BYTES)

// LDS: resident weights + double-buffered input chunks (R6-proven).
#define KC    64                      // k per chunk
#define NCH   (HH / KC)               // 8 chunks per GEMV
#define IBR   68                      // input buffer row pitch (floats)
#define IBF   (BB * IBR)              // 2176 floats per chunk buffer
#define WLDS  32768                   // weight region (floats)
#define LDS_BYTES ((WLDS + 2 * IBF) * 4)   // 148480 <= 163840

// ---- self-timed dataflow (R1/R6-proven), B rebalanced to 16 WGs/layer ----
// done_A[i]: +1 per A-WG (32 ZR + 8 hU = 40/layer) per completed step.
// done_B[i]: +1 per B-WG (16/layer) per completed step.
//   A(i,t): U-side needs done_B[i-1] >= 16(t+1)  (inp; i=0 reads x, no wait)
//           W-side + stores need done_B[i] >= 16t (prev ready + gate ack;
//           also guarantees all 16 B WGs' staged reads of t-1 are done)
//   B(i,t): needs done_A[i] >= 40(t+1); state stores need done_A[i+1] >= 40t
// R6 post-mortem: B at 64 cols was 2x the per-WG LDS traffic of ZR's W-half
// and the critical-path long pole; 16x32-col B WGs halve it and use the 64
// idle CUs (192 -> 224 WGs).
#define DONE_A(f, i) ((f) + (i) * FLAG_STRIDE)
#define DONE_B(f, i) ((f) + (8 + (i)) * FLAG_STRIDE)
#define SPIN_CAP (1 << 22)     // ~1.5 s worst case, then free-run (no hang)

__device__ __forceinline__ void wg_wait(int* cnt, int target, int& dead) {
    if (threadIdx.x == 0 && !dead) {
        int spins = 0;
        while (__hip_atomic_load(cnt, __ATOMIC_RELAXED,
                                 __HIP_MEMORY_SCOPE_AGENT) < target) {
            __builtin_amdgcn_s_sleep(2);
            if (++spins > SPIN_CAP) { dead = 1; break; }
        }
        // acquire: invalidate L1/L2 so subsequent plain loads see IC data
        (void)__hip_atomic_load(cnt, __ATOMIC_ACQUIRE,
                                __HIP_MEMORY_SCOPE_AGENT);
    }
    __syncthreads();
}

__device__ __forceinline__ void wg_post(int* cnt) {
    asm volatile("" ::: "memory");
    __builtin_amdgcn_s_waitcnt(0);   // own stores ack'd at coherence point
    __syncthreads();                 // all threads drained
    if (threadIdx.x == 0)
        atomicAdd(cnt, 1);           // device-scope, IC-level
}

__device__ __forceinline__ void pub_store(float* p, float v) {
    __hip_atomic_store(p, v, __ATOMIC_RELAXED, __HIP_MEMORY_SCOPE_AGENT);
}
__device__ __forceinline__ float sigf(float v) {
    return 1.0f / (1.0f + __expf(-v));
}

// 16-fmaf register tile (4 rows x 4 cols) on one weight float4
#define FMA16(WV, E0, E1, E2, E3)                                           \
    acc[0][0] = fmaf(E0, WV.x, acc[0][0]); acc[0][1] = fmaf(E0, WV.y, acc[0][1]); \
    acc[0][2] = fmaf(E0, WV.z, acc[0][2]); acc[0][3] = fmaf(E0, WV.w, acc[0][3]); \
    acc[1][0] = fmaf(E1, WV.x, acc[1][0]); acc[1][1] = fmaf(E1, WV.y, acc[1][1]); \
    acc[1][2] = fmaf(E1, WV.z, acc[1][2]); acc[1][3] = fmaf(E1, WV.w, acc[1][3]); \
    acc[2][0] = fmaf(E2, WV.x, acc[2][0]); acc[2][1] = fmaf(E2, WV.y, acc[2][1]); \
    acc[2][2] = fmaf(E2, WV.z, acc[2][2]); acc[2][3] = fmaf(E2, WV.w, acc[2][3]); \
    acc[3][0] = fmaf(E3, WV.x, acc[3][0]); acc[3][1] = fmaf(E3, WV.y, acc[3][1]); \
    acc[3][2] = fmaf(E3, WV.z, acc[3][2]); acc[3][3] = fmaf(E3, WV.w, acc[3][3])

// WG roles (logical wg 0..223), TPB=256. Buffers b-major (slice[b*512+col]).
//   wg   0..127: A z/r. grp=wg>>4: i=grp>>1, g=grp&1; 32 cols.
//       compute map: ksc=tid&3 (16 k/chunk), cq=(tid>>2)&7, bq=tid>>5
//       weights: lds[(k*8+cq)*4..] = M[k][col0+cq*4..+3]; U at 0, W at 16384
//   wg 128..159: A hU. i=(wg-128)>>3; 64 cols.
//       compute map: ks2=tid&1 (32 k/chunk), cq=(tid>>1)&15, bq=tid>>5
//       weights: lds[(k*16+cq)*4..] = U2[k][col0+cq*4..+3]
//   wg 160..223: B. w3=wg-160: i=w3>>4; 32 cols col0B=(w3&15)*32.
//       compute map = ZR map; weights lds[(k*8+cq)*4..] = W2[k][col0B+...];
//       staged input is the product r*p (computed at staging; same math).
//   staging map (all roles): sb=tid>>4 (rows sb, sb+16), sk=tid&15 (float4).

__global__ __launch_bounds__(TPB) void gru_wave(
    const float* __restrict__ x,    // [B,T,D]
    const float* __restrict__ Wp,   // [L,3,H,H]
    const float* __restrict__ Up,   // [L,3,D,H]
    float* __restrict__ out,        // [B,T,H]
    float* __restrict__ ws)
{
    extern __shared__ float lds[];

    const int bid = blockIdx.x;
    const int wg  = (bid & 7) * 28 + (bid >> 3);   // XCD-contiguous logical id
    const int tid = threadIdx.x;
    const int sb  = tid >> 4;          // staging row (and row+16)
    const int sk  = tid & 15;          // staging float4 within 64-k row chunk

    float* state = ws;                         // [L][2][B][H]
    float* zbuf  = state + LL * 2 * HB;        // [L][B][H]
    float* rbuf  = zbuf + LL * HB;
    float* hUbuf = rbuf + LL * HB;
    int*   flags = (int*)(ws + DATA_FLOATS);

    float* ib0 = lds + WLDS;
    float* ib1 = ib0 + IBF;

    const bool isZR = wg < 128;
    const bool isHU = (wg >= 128) && (wg < 160);

    int iA = 0, gA = 0, col0 = 0, iB = 0, col0B = 0;
    if (isZR) { int grp = wg >> 4; iA = grp >> 1; gA = grp & 1; col0 = (wg & 15) * 32; }
    else if (isHU) { int w2 = wg - 128; iA = w2 >> 3; col0 = (w2 & 7) * 64; }
    else { int w3 = wg - 160; iB = w3 >> 4; col0B = (w3 & 15) * 32; }

    // ---- one-time weight staging: straight row-major float4 copy ----
    if (isZR) {
        const float* Um = Up + (size_t)(iA * 3 + gA) * DD * HH + col0;
        const float* Wm = Wp + (size_t)(iA * 3 + gA) * HH * HH + col0;
        for (int u = tid; u < 4096; u += TPB) {      // u = k*8 + cq
            int k = u >> 3, cc = u & 7;
            *(float4*)&lds[u * 4]         = *(const float4*)&Um[(size_t)k * HH + cc * 4];
            *(float4*)&lds[16384 + u * 4] = *(const float4*)&Wm[(size_t)k * HH + cc * 4];
        }
    } else if (isHU) {
        const float* Mm = Up + (size_t)(iA * 3 + 2) * DD * HH + col0;
        for (int u = tid; u < 8192; u += TPB) {      // u = k*16 + cq
            int k = u >> 4, cc = u & 15;
            *(float4*)&lds[u * 4] = *(const float4*)&Mm[(size_t)k * HH + cc * 4];
        }
    } else {
        const float* Mm = Wp + (size_t)(iB * 3 + 2) * HH * HH + col0B;
        for (int u = tid; u < 4096; u += TPB) {      // u = k*8 + cq
            int k = u >> 3, cc = u & 7;
            *(float4*)&lds[u * 4] = *(const float4*)&Mm[(size_t)k * HH + cc * 4];
        }
    }
    __syncthreads();

    int dead = 0;

    if (isZR) {
        const int ksc = tid & 3, cq = (tid >> 2) & 7, bq = tid >> 5;
        const int colq = col0 + cq * 4;
        float* dst = (gA == 0 ? zbuf : rbuf) + (size_t)iA * HB;
        int* cb_up = (iA > 0) ? DONE_B(flags, iA - 1) : nullptr;
        int* cb_my = DONE_B(flags, iA);
        int* c_my  = DONE_A(flags, iA);
        for (int t = 0; t < TT; ++t) {
            float acc[4][4] = {};
            // ================= U-half (staged) =================
            if (cb_up) wg_wait(cb_up, 16 * (t + 1), dead);
            {
                const float* src; size_t rstr;
                if (iA == 0) {
                    src = x + (size_t)sb * TT * DD + (size_t)t * DD + sk * 4;
                    rstr = (size_t)16 * TT * DD;
                } else {
                    src = state + (size_t)((iA - 1) * 2 + (t & 1)) * HB + sb * HH + sk * 4;
                    rstr = (size_t)16 * HH;
                }
                float4 g0 = *(const float4*)&src[0];
                float4 g1 = *(const float4*)&src[rstr];
                src += KC;
                *(float4*)&ib0[sb * IBR + sk * 4]        = g0;
                *(float4*)&ib0[(sb + 16) * IBR + sk * 4] = g1;
                g0 = *(const float4*)&src[0]; g1 = *(const float4*)&src[rstr]; src += KC;
                __syncthreads();
                float *rb = ib0, *nb = ib1;
                const float* wp0 = lds + (ksc * 16 * 8 + cq) * 4;
                for (int c = 0; c < NCH; ++c) {
                    const float* r0 = rb + (bq * 4 + 0) * IBR + ksc * 16;
                    const float* r1 = rb + (bq * 4 + 1) * IBR + ksc * 16;
                    const float* r2 = rb + (bq * 4 + 2) * IBR + ksc * 16;
                    const float* r3 = rb + (bq * 4 + 3) * IBR + ksc * 16;
                    const float* wp = wp0 + c * (KC * 8 * 4);
                    #pragma unroll
                    for (int kk = 0; kk < 4; ++kk) {
                        float4 x0 = *(const float4*)&r0[kk * 4];
                        float4 x1 = *(const float4*)&r1[kk * 4];
                        float4 x2 = *(const float4*)&r2[kk * 4];
                        float4 x3 = *(const float4*)&r3[kk * 4];
                        #pragma unroll
                        for (int j = 0; j < 4; ++j) {
                            float4 wv = *(const float4*)&wp[(kk * 4 + j) * 32];
                            FMA16(wv, (&x0.x)[j], (&x1.x)[j], (&x2.x)[j], (&x3.x)[j]);
                        }
                    }
                    if (c < NCH - 1) {
                        *(float4*)&nb[sb * IBR + sk * 4]        = g0;
                        *(float4*)&nb[(sb + 16) * IBR + sk * 4] = g1;
                        if (c < NCH - 2) {
                            g0 = *(const float4*)&src[0];
                            g1 = *(const float4*)&src[rstr];
                            src += KC;
                        }
                    }
                    __syncthreads();
                    float* tp = rb; rb = nb; nb = tp;
                }
            }
            // ================= W-half (staged) =================
            wg_wait(cb_my, 16 * t, dead);
            {
                const float* src = state + (size_t)(iA * 2 + ((t + 1) & 1)) * HB
                                 + sb * HH + sk * 4;
                const size_t rstr = (size_t)16 * HH;
                float4 g0 = *(const float4*)&src[0];
                float4 g1 = *(const float4*)&src[rstr];
                src += KC;
                *(float4*)&ib0[sb * IBR + sk * 4]        = g0;
                *(float4*)&ib0[(sb + 16) * IBR + sk * 4] = g1;
                g0 = *(const float4*)&src[0]; g1 = *(const float4*)&src[rstr]; src += KC;
                __syncthreads();
                float *rb = ib0, *nb = ib1;
                const float* wp0 = lds + 16384 + (ksc * 16 * 8 + cq) * 4;
                for (int c = 0; c < NCH; ++c) {
                    const float* r0 = rb + (bq * 4 + 0) * IBR + ksc * 16;
                    const float* r1 = rb + (bq * 4 + 1) * IBR + ksc * 16;
                    const float* r2 = rb + (bq * 4 + 2) * IBR + ksc * 16;
                    const float* r3 = rb + (bq * 4 + 3) * IBR + ksc * 16;
                    const float* wp = wp0 + c * (KC * 8 * 4);
                    #pragma unroll
                    for (int kk = 0; kk < 4; ++kk) {
                        float4 x0 = *(const float4*)&r0[kk * 4];
                        float4 x1 = *(const float4*)&r1[kk * 4];
                        float4 x2 = *(const float4*)&r2[kk * 4];
                        float4 x3 = *(const float4*)&r3[kk * 4];
                        #pragma unroll
                        for (int j = 0; j < 4; ++j) {
                            float4 wv = *(const float4*)&wp[(kk * 4 + j) * 32];
                            FMA16(wv, (&x0.x)[j], (&x1.x)[j], (&x2.x)[j], (&x3.x)[j]);
                        }
                    }
                    if (c < NCH - 1) {
                        *(float4*)&nb[sb * IBR + sk * 4]        = g0;
                        *(float4*)&nb[(sb + 16) * IBR + sk * 4] = g1;
                        if (c < NCH - 2) {
                            g0 = *(const float4*)&src[0];
                            g1 = *(const float4*)&src[rstr];
                            src += KC;
                        }
                    }
                    __syncthreads();
                    float* tp = rb; rb = nb; nb = tp;
                }
            }
            // reduce over ksc (lane quads share (bq,cq)); lane ksc stores row ksc
            #pragma unroll
            for (int i = 0; i < 4; ++i)
                #pragma unroll
                for (int j = 0; j < 4; ++j) {
                    float v = acc[i][j];
                    v += __shfl_xor(v, 1, 64);
                    v += __shfl_xor(v, 2, 64);
                    acc[i][j] = v;
                }
            float s0, s1, s2, s3;
            if      (ksc == 0) { s0 = acc[0][0]; s1 = acc[0][1]; s2 = acc[0][2]; s3 = acc[0][3]; }
            else if (ksc == 1) { s0 = acc[1][0]; s1 = acc[1][1]; s2 = acc[1][2]; s3 = acc[1][3]; }
            else if (ksc == 2) { s0 = acc[2][0]; s1 = acc[2][1]; s2 = acc[2][2]; s3 = acc[2][3]; }
            else               { s0 = acc[3][0]; s1 = acc[3][1]; s2 = acc[3][2]; s3 = acc[3][3]; }
            float* drow = dst + (size_t)(bq * 4 + ksc) * HH + colq;
            pub_store(&drow[0], sigf(s0));
            pub_store(&drow[1], sigf(s1));
            pub_store(&drow[2], sigf(s2));
            pub_store(&drow[3], sigf(s3));
            wg_post(c_my);
        }
    } else if (isHU) {
        const int ks2 = tid & 1, cq = (tid >> 1) & 15, bq = tid >> 5;
        const int colq = col0 + cq * 4;
        float* hu = hUbuf + (size_t)iA * HB;
        int* cb_up = (iA > 0) ? DONE_B(flags, iA - 1) : nullptr;
        int* cb_my = DONE_B(flags, iA);
        int* c_my  = DONE_A(flags, iA);
        for (int t = 0; t < TT; ++t) {
            float acc[4][4] = {};
            if (cb_up) wg_wait(cb_up, 16 * (t + 1), dead);
            {
                const float* src; size_t rstr;
                if (iA == 0) {
                    src = x + (size_t)sb * TT * DD + (size_t)t * DD + sk * 4;
                    rstr = (size_t)16 * TT * DD;
                } else {
                    src = state + (size_t)((iA - 1) * 2 + (t & 1)) * HB + sb * HH + sk * 4;
                    rstr = (size_t)16 * HH;
                }
                float4 g0 = *(const float4*)&src[0];
                float4 g1 = *(const float4*)&src[rstr];
                src += KC;
                *(float4*)&ib0[sb * IBR + sk * 4]        = g0;
                *(float4*)&ib0[(sb + 16) * IBR + sk * 4] = g1;
                g0 = *(const float4*)&src[0]; g1 = *(const float4*)&src[rstr]; src += KC;
                __syncthreads();
                float *rb = ib0, *nb = ib1;
                const float* wp0 = lds + (ks2 * 32 * 16 + cq) * 4;
                for (int c = 0; c < NCH; ++c) {
                    const float* r0 = rb + (bq * 4 + 0) * IBR + ks2 * 32;
                    const float* r1 = rb + (bq * 4 + 1) * IBR + ks2 * 32;
                    const float* r2 = rb + (bq * 4 + 2) * IBR + ks2 * 32;
                    const float* r3 = rb + (bq * 4 + 3) * IBR + ks2 * 32;
                    const float* wp = wp0 + c * (KC * 16 * 4);
                    #pragma unroll
                    for (int kk = 0; kk < 8; ++kk) {
                        float4 x0 = *(const float4*)&r0[kk * 4];
                        float4 x1 = *(const float4*)&r1[kk * 4];
                        float4 x2 = *(const float4*)&r2[kk * 4];
                        float4 x3 = *(const float4*)&r3[kk * 4];
                        #pragma unroll
                        for (int j = 0; j < 4; ++j) {
                            float4 wv = *(const float4*)&wp[(kk * 4 + j) * 64];
                            FMA16(wv, (&x0.x)[j], (&x1.x)[j], (&x2.x)[j], (&x3.x)[j]);
                        }
                    }
                    if (c < NCH - 1) {
                        *(float4*)&nb[sb * IBR + sk * 4]        = g0;
                        *(float4*)&nb[(sb + 16) * IBR + sk * 4] = g1;
                        if (c < NCH - 2) {
                            g0 = *(const float4*)&src[0];
                            g1 = *(const float4*)&src[rstr];
                            src += KC;
                        }
                    }
                    __syncthreads();
                    float* tp = rb; rb = nb; nb = tp;
                }
            }
            // store-ack (B consumed hU(t-1)); then reduce over k-halves
            wg_wait(cb_my, 16 * t, dead);
            #pragma unroll
            for (int i = 0; i < 4; ++i)
                #pragma unroll
                for (int j = 0; j < 4; ++j) {
                    float v = acc[i][j];
                    v += __shfl_xor(v, 1, 64);
                    acc[i][j] = v;
                }
            float r0v[4], r1v[4];
            if (ks2 == 0) {
                r0v[0]=acc[0][0]; r0v[1]=acc[0][1]; r0v[2]=acc[0][2]; r0v[3]=acc[0][3];
                r1v[0]=acc[1][0]; r1v[1]=acc[1][1]; r1v[2]=acc[1][2]; r1v[3]=acc[1][3];
            } else {
                r0v[0]=acc[2][0]; r0v[1]=acc[2][1]; r0v[2]=acc[2][2]; r0v[3]=acc[2][3];
                r1v[0]=acc[3][0]; r1v[1]=acc[3][1]; r1v[2]=acc[3][2]; r1v[3]=acc[3][3];
            }
            const int b0 = bq * 4 + ks2 * 2;
            float* h0 = hu + (size_t)b0 * HH + colq;
            float* h1 = hu + (size_t)(b0 + 1) * HH + colq;
            pub_store(&h0[0], r0v[0]); pub_store(&h0[1], r0v[1]);
            pub_store(&h0[2], r0v[2]); pub_store(&h0[3], r0v[3]);
            pub_store(&h1[0], r1v[0]); pub_store(&h1[1], r1v[1]);
            pub_store(&h1[2], r1v[2]); pub_store(&h1[3], r1v[3]);
            wg_post(c_my);
        }
    } else {
        const int ksc = tid & 3, cq = (tid >> 2) & 7, bq = tid >> 5;
        const int colq = col0B + cq * 4;
        const float* rbase = rbuf + (size_t)iB * HB;
        const float* hu    = hUbuf + (size_t)iB * HB;
        const float* zz    = zbuf + (size_t)iB * HB;
        int* c_my = DONE_B(flags, iB);
        for (int t = 0; t < TT; ++t) {
            // all gates of step t ready (z, r, hU) — implies prow complete
            wg_wait(DONE_A(flags, iB), 40 * (t + 1), dead);
            const float* prow = state + (size_t)(iB * 2 + ((t + 1) & 1)) * HB;
            float acc[4][4] = {};
            {
                // staged product rp = r*p (computed at staging; same math order)
                const float* rs = rbase + (size_t)sb * HH + sk * 4;
                const float* ps = prow  + (size_t)sb * HH + sk * 4;
                const size_t rstr = (size_t)16 * HH;
                float4 g0r = *(const float4*)&rs[0],   g0p = *(const float4*)&ps[0];
                float4 g1r = *(const float4*)&rs[rstr], g1p = *(const float4*)&ps[rstr];
                rs += KC; ps += KC;
                *(float4*)&ib0[sb * IBR + sk * 4] =
                    make_float4(g0r.x * g0p.x, g0r.y * g0p.y, g0r.z * g0p.z, g0r.w * g0p.w);
                *(float4*)&ib0[(sb + 16) * IBR + sk * 4] =
                    make_float4(g1r.x * g1p.x, g1r.y * g1p.y, g1r.z * g1p.z, g1r.w * g1p.w);
                g0r = *(const float4*)&rs[0];   g0p = *(const float4*)&ps[0];
                g1r = *(const float4*)&rs[rstr]; g1p = *(const float4*)&ps[rstr];
                rs += KC; ps += KC;
                __syncthreads();
                float *rb = ib0, *nb = ib1;
                const float* wp0 = lds + (ksc * 16 * 8 + cq) * 4;
                for (int c = 0; c < NCH; ++c) {
                    const float* r0 = rb + (bq * 4 + 0) * IBR + ksc * 16;
                    const float* r1 = rb + (bq * 4 + 1) * IBR + ksc * 16;
                    const float* r2 = rb + (bq * 4 + 2) * IBR + ksc * 16;
                    const float* r3 = rb + (bq * 4 + 3) * IBR + ksc * 16;
                    const float* wp = wp0 + c * (KC * 8 * 4);
                    #pragma unroll
                    for (int kk = 0; kk < 4; ++kk) {
                        float4 x0 = *(const float4*)&r0[kk * 4];
                        float4 x1 = *(const float4*)&r1[kk * 4];
                        float4 x2 = *(const float4*)&r2[kk * 4];
                        float4 x3 = *(const float4*)&r3[kk * 4];
                        #pragma unroll
                        for (int j = 0; j < 4; ++j) {
                            float4 wv = *(const float4*)&wp[(kk * 4 + j) * 32];
                            FMA16(wv, (&x0.x)[j], (&x1.x)[j], (&x2.x)[j], (&x3.x)[j]);
                        }
                    }
                    if (c < NCH - 1) {
                        *(float4*)&nb[sb * IBR + sk * 4] =
                            make_float4(g0r.x * g0p.x, g0r.y * g0p.y, g0r.z * g0p.z, g0r.w * g0p.w);
                        *(float4*)&nb[(sb + 16) * IBR + sk * 4] =
                            make_float4(g1r.x * g1p.x, g1r.y * g1p.y, g1r.z * g1p.z, g1r.w * g1p.w);
                        if (c < NCH - 2) {
                            g0r = *(const float4*)&rs[0];   g0p = *(const float4*)&ps[0];
                            g1r = *(const float4*)&rs[rstr]; g1p = *(const float4*)&ps[rstr];
                            rs += KC; ps += KC;
                        }
                    }
                    __syncthreads();
                    float* tp = rb; rb = nb; nb = tp;
                }
            }
            // state(t-2) slot overwrite-ack: downstream A(i+1,t-1) done
            if (iB < 3) wg_wait(DONE_A(flags, iB + 1), 40 * t, dead);
            #pragma unroll
            for (int i = 0; i < 4; ++i)
                #pragma unroll
                for (int j = 0; j < 4; ++j) {
                    float v = acc[i][j];
                    v += __shfl_xor(v, 1, 64);
                    v += __shfl_xor(v, 2, 64);
                    acc[i][j] = v;
                }
            float s0, s1, s2, s3;
            if      (ksc == 0) { s0 = acc[0][0]; s1 = acc[0][1]; s2 = acc[0][2]; s3 = acc[0][3]; }
            else if (ksc == 1) { s0 = acc[1][0]; s1 = acc[1][1]; s2 = acc[1][2]; s3 = acc[1][3]; }
            else if (ksc == 2) { s0 = acc[2][0]; s1 = acc[2][1]; s2 = acc[2][2]; s3 = acc[2][3]; }
            else               { s0 = acc[3][0]; s1 = acc[3][1]; s2 = acc[3][2]; s3 = acc[3][3]; }
            float* stNew = state + (size_t)(iB * 2 + (t & 1)) * HB;
            const int b = bq * 4 + ksc;
            float4 hu4 = *(const float4*)&hu[(size_t)b * HH + colq];
            float4 zz4 = *(const float4*)&zz[(size_t)b * HH + colq];
            float4 pv4 = *(const float4*)&prow[(size_t)b * HH + colq];
            float av[4] = {s0, s1, s2, s3};
            float4 o4;
            #pragma unroll
            for (int j = 0; j < 4; ++j) {
                float h  = tanhf(av[j] + (&hu4.x)[j]);
                float zg = (&zz4.x)[j];
                float s  = zg * ((&pv4.x)[j] - h) + h;   // (1-z)*h + z*prev
                pub_store(&stNew[(size_t)b * HH + colq + j], s);
                (&o4.x)[j] = s;
            }
            if (iB == LL - 1)
                *(float4*)&out[((size_t)b * TT + t) * HH + colq] = o4;
            wg_post(c_my);
        }
    }
}

extern "C" void kernel_launch(void* const* d_in, const int* in_sizes, int n_in,
                              void* d_out, int out_size, void* d_ws, size_t ws_size,
                              hipStream_t stream) {
    const float* x  = (const float*)d_in[0];  // [32,512,512]
    const float* Wp = (const float*)d_in[1];  // [4,3,512,512]
    const float* Up = (const float*)d_in[2];  // [4,3,512,512]
    float* out = (float*)d_out;
    float* ws  = (float*)d_ws;

    // Sentinel 1: workspace too small -> absmax ~8.5e37
    if (ws_size < WS_NEED_BYTES) {
        hipMemsetAsync(d_out, 0x7e, (size_t)out_size * sizeof(float), stream);
        return;
    }

    // Host-side zero of state (t=0 prev) and counters each call (R1-proven).
    hipMemsetAsync(ws, 0, (size_t)STATE_FLOATS * sizeof(float), stream);
    hipMemsetAsync(ws + DATA_FLOATS, 0, FLAGS_BYTES, stream);

    hipLaunchKernelGGL(gru_wave, dim3(NWG), dim3(TPB), LDS_BYTES, stream,
                       x, Wp, Up, out, ws);
    // Sentinel 2: launch rejected -> absmax ~3.4e38
    hipError_t err = hipGetLastError();
    if (err != hipSuccess)
        hipMemsetAsync(d_out, 0x7f, (size_t)out_size * sizeof(float), stream);
}